// Round 1
// baseline (3011.855 us; speedup 1.0000x reference)
//
#include <hip/hip_runtime.h>
#include <math.h>

#define NN 50000
#define EE 800000

__device__ __forceinline__ float sigmoidf_(float x) { return 1.0f / (1.0f + __expf(-x)); }

// ---------------- node history LSTM + xu build ----------------
__global__ __launch_bounds__(256) void node_lstm_k(
    const float* __restrict__ x, const float* __restrict__ u,
    const float* __restrict__ h0, const float* __restrict__ c0,
    const float* __restrict__ Wih, const float* __restrict__ Whh,
    const float* __restrict__ bih, const float* __restrict__ bhh,
    float* __restrict__ xu_out, float* __restrict__ h_out, float* __restrict__ c_out)
{
    __shared__ float sWih[80 * 37];
    __shared__ float sWhh[80 * 20];
    __shared__ float sb[80];
    for (int i = threadIdx.x; i < 80 * 37; i += 256) sWih[i] = Wih[i];
    for (int i = threadIdx.x; i < 80 * 20; i += 256) sWhh[i] = Whh[i];
    if (threadIdx.x < 80) sb[threadIdx.x] = bih[threadIdx.x] + bhh[threadIdx.x];
    __syncthreads();
    int n = blockIdx.x * 256 + threadIdx.x;
    if (n >= NN) return;

    float xu[37];
#pragma unroll
    for (int k = 0; k < 5; k++) xu[k] = x[n * 5 + k];
#pragma unroll
    for (int k = 0; k < 32; k++) xu[5 + k] = u[n * 32 + k];
#pragma unroll
    for (int k = 0; k < 37; k++) xu_out[(size_t)n * 37 + k] = xu[k];

    float h[20];
#pragma unroll
    for (int k = 0; k < 20; k++) h[k] = h0[n * 20 + k];

#pragma unroll 1
    for (int r = 0; r < 20; r++) {
        float gi = sb[r], gf = sb[20 + r], gg = sb[40 + r], go = sb[60 + r];
#pragma unroll
        for (int k = 0; k < 37; k++) {
            float v = xu[k];
            gi = fmaf(v, sWih[r * 37 + k], gi);
            gf = fmaf(v, sWih[(20 + r) * 37 + k], gf);
            gg = fmaf(v, sWih[(40 + r) * 37 + k], gg);
            go = fmaf(v, sWih[(60 + r) * 37 + k], go);
        }
#pragma unroll
        for (int k = 0; k < 20; k++) {
            float v = h[k];
            gi = fmaf(v, sWhh[r * 20 + k], gi);
            gf = fmaf(v, sWhh[(20 + r) * 20 + k], gf);
            gg = fmaf(v, sWhh[(40 + r) * 20 + k], gg);
            go = fmaf(v, sWhh[(60 + r) * 20 + k], go);
        }
        float cr = c0[n * 20 + r];
        float cn = sigmoidf_(gf) * cr + sigmoidf_(gi) * tanhf(gg);
        float hn = sigmoidf_(go) * tanhf(cn);
        h_out[n * 20 + r] = hn;
        c_out[n * 20 + r] = cn;
    }
}

// ---------------- edge MLP + atomic aggregation ----------------
template <int F, bool DO_CNT>
__global__ __launch_bounds__(256) void edge_mlp_k(
    const float* __restrict__ feat,
    const int* __restrict__ row, const int* __restrict__ col,
    const float* __restrict__ eattr,
    const float* __restrict__ W1, const float* __restrict__ b1,
    const float* __restrict__ W2, const float* __restrict__ b2,
    float* __restrict__ agg, float* __restrict__ cnt)
{
    constexpr int IN = 2 * F + 4;
    __shared__ __align__(16) float sW1[IN * 64];
    __shared__ __align__(16) float sW2[64 * 32];
    __shared__ float sb1[64];
    __shared__ float sb2[32];
    for (int i = threadIdx.x; i < IN * 64; i += 256) sW1[i] = W1[i];
    for (int i = threadIdx.x; i < 64 * 32; i += 256) sW2[i] = W2[i];
    if (threadIdx.x < 64) sb1[threadIdx.x] = b1[threadIdx.x];
    if (threadIdx.x < 32) sb2[threadIdx.x] = b2[threadIdx.x];
    __syncthreads();
    int e = blockIdx.x * 256 + threadIdx.x;
    if (e >= EE) return;

    int r = row[e], c = col[e];
    float h[IN];
    const float* fr = &feat[(size_t)r * F];
    const float* fc = &feat[(size_t)c * F];
#pragma unroll
    for (int k = 0; k < F; k++) h[k] = fr[k];
#pragma unroll
    for (int k = 0; k < F; k++) h[F + k] = fc[k];
    float4 ev = *(const float4*)&eattr[(size_t)e * 4];
    h[2 * F] = ev.x; h[2 * F + 1] = ev.y; h[2 * F + 2] = ev.z; h[2 * F + 3] = ev.w;

    float out[32];
#pragma unroll
    for (int m = 0; m < 32; m++) out[m] = sb2[m];

#pragma unroll 1
    for (int j = 0; j < 64; j += 4) {
        float s[4] = {sb1[j], sb1[j + 1], sb1[j + 2], sb1[j + 3]};
#pragma unroll
        for (int k = 0; k < IN; k++) {
            float4 w = *(const float4*)&sW1[k * 64 + j];
            s[0] = fmaf(h[k], w.x, s[0]);
            s[1] = fmaf(h[k], w.y, s[1]);
            s[2] = fmaf(h[k], w.z, s[2]);
            s[3] = fmaf(h[k], w.w, s[3]);
        }
        s[0] = fmaxf(s[0], 0.f); s[1] = fmaxf(s[1], 0.f);
        s[2] = fmaxf(s[2], 0.f); s[3] = fmaxf(s[3], 0.f);
#pragma unroll
        for (int jj = 0; jj < 4; jj++) {
#pragma unroll
            for (int m = 0; m < 32; m += 4) {
                float4 w = *(const float4*)&sW2[(j + jj) * 32 + m];
                out[m]     = fmaf(s[jj], w.x, out[m]);
                out[m + 1] = fmaf(s[jj], w.y, out[m + 1]);
                out[m + 2] = fmaf(s[jj], w.z, out[m + 2]);
                out[m + 3] = fmaf(s[jj], w.w, out[m + 3]);
            }
        }
    }

    float* dst = &agg[(size_t)c * 32];
#pragma unroll
    for (int m = 0; m < 32; m++) atomicAdd(&dst[m], out[m]);
    if (DO_CNT) atomicAdd(&cnt[c], 1.0f);
}

// ---------------- edge history LSTM + full build ----------------
__global__ __launch_bounds__(256) void edge_lstm_k(
    const float* __restrict__ agg, const float* __restrict__ cnt,
    const float* __restrict__ h0, const float* __restrict__ c0,
    const float* __restrict__ Wih, const float* __restrict__ Whh,
    const float* __restrict__ bih, const float* __restrict__ bhh,
    const float* __restrict__ node_h,
    float* __restrict__ h_out, float* __restrict__ c_out, float* __restrict__ full)
{
    __shared__ float sWih[32 * 32];
    __shared__ float sWhh[32 * 8];
    __shared__ float sb[32];
    for (int i = threadIdx.x; i < 32 * 32; i += 256) sWih[i] = Wih[i];
    for (int i = threadIdx.x; i < 32 * 8; i += 256) sWhh[i] = Whh[i];
    if (threadIdx.x < 32) sb[threadIdx.x] = bih[threadIdx.x] + bhh[threadIdx.x];
    __syncthreads();
    int n = blockIdx.x * 256 + threadIdx.x;
    if (n >= NN) return;

    float inv = 1.0f / fmaxf(cnt[n], 1.0f);
    float msg[32];
#pragma unroll
    for (int k = 0; k < 32; k++) msg[k] = agg[(size_t)n * 32 + k] * inv;
    float h[8];
#pragma unroll
    for (int k = 0; k < 8; k++) h[k] = h0[n * 8 + k];
    float hn_arr[8];

#pragma unroll
    for (int r = 0; r < 8; r++) {
        float gi = sb[r], gf = sb[8 + r], gg = sb[16 + r], go = sb[24 + r];
#pragma unroll
        for (int k = 0; k < 32; k++) {
            float v = msg[k];
            gi = fmaf(v, sWih[r * 32 + k], gi);
            gf = fmaf(v, sWih[(8 + r) * 32 + k], gf);
            gg = fmaf(v, sWih[(16 + r) * 32 + k], gg);
            go = fmaf(v, sWih[(24 + r) * 32 + k], go);
        }
#pragma unroll
        for (int k = 0; k < 8; k++) {
            float v = h[k];
            gi = fmaf(v, sWhh[r * 8 + k], gi);
            gf = fmaf(v, sWhh[(8 + r) * 8 + k], gf);
            gg = fmaf(v, sWhh[(16 + r) * 8 + k], gg);
            go = fmaf(v, sWhh[(24 + r) * 8 + k], go);
        }
        float cr = c0[n * 8 + r];
        float cn = sigmoidf_(gf) * cr + sigmoidf_(gi) * tanhf(gg);
        float hn = sigmoidf_(go) * tanhf(cn);
        h_out[n * 8 + r] = hn;
        c_out[n * 8 + r] = cn;
        hn_arr[r] = hn;
    }
#pragma unroll
    for (int k = 0; k < 20; k++) full[(size_t)n * 28 + k] = node_h[n * 20 + k];
#pragma unroll
    for (int k = 0; k < 8; k++) full[(size_t)n * 28 + 20 + k] = hn_arr[k];
}

// ---------------- output node MLP ----------------
__global__ __launch_bounds__(256) void node_out_k(
    const float* __restrict__ full, const float* __restrict__ agg2, const float* __restrict__ cnt,
    const float* __restrict__ W1, const float* __restrict__ b1,
    const float* __restrict__ W2, const float* __restrict__ b2,
    float* __restrict__ out)
{
    __shared__ __align__(16) float sW1[60 * 64];
    __shared__ __align__(16) float sW2[64 * 4];
    __shared__ float sb1[64];
    __shared__ float sb2[4];
    for (int i = threadIdx.x; i < 60 * 64; i += 256) sW1[i] = W1[i];
    for (int i = threadIdx.x; i < 64 * 4; i += 256) sW2[i] = W2[i];
    if (threadIdx.x < 64) sb1[threadIdx.x] = b1[threadIdx.x];
    if (threadIdx.x < 4) sb2[threadIdx.x] = b2[threadIdx.x];
    __syncthreads();
    int n = blockIdx.x * 256 + threadIdx.x;
    if (n >= NN) return;

    float in[60];
#pragma unroll
    for (int k = 0; k < 28; k++) in[k] = full[(size_t)n * 28 + k];
    float inv = 1.0f / fmaxf(cnt[n], 1.0f);
#pragma unroll
    for (int k = 0; k < 32; k++) in[28 + k] = agg2[(size_t)n * 32 + k] * inv;

    float o[4] = {sb2[0], sb2[1], sb2[2], sb2[3]};
#pragma unroll 1
    for (int j = 0; j < 64; j += 4) {
        float s[4] = {sb1[j], sb1[j + 1], sb1[j + 2], sb1[j + 3]};
#pragma unroll
        for (int k = 0; k < 60; k++) {
            float4 w = *(const float4*)&sW1[k * 64 + j];
            s[0] = fmaf(in[k], w.x, s[0]);
            s[1] = fmaf(in[k], w.y, s[1]);
            s[2] = fmaf(in[k], w.z, s[2]);
            s[3] = fmaf(in[k], w.w, s[3]);
        }
#pragma unroll
        for (int jj = 0; jj < 4; jj++) {
            float sv = fmaxf(s[jj], 0.0f);
            float4 w = *(const float4*)&sW2[(j + jj) * 4];
            o[0] = fmaf(sv, w.x, o[0]);
            o[1] = fmaf(sv, w.y, o[1]);
            o[2] = fmaf(sv, w.z, o[2]);
            o[3] = fmaf(sv, w.w, o[3]);
        }
    }
#pragma unroll
    for (int m = 0; m < 4; m++) out[n * 4 + m] = o[m];
}

extern "C" void kernel_launch(void* const* d_in, const int* in_sizes, int n_in,
                              void* d_out, int out_size, void* d_ws, size_t ws_size,
                              hipStream_t stream) {
    (void)in_sizes; (void)n_in; (void)out_size; (void)ws_size;
    const float* x      = (const float*)d_in[0];
    const float* u      = (const float*)d_in[1];
    const int*   ei     = (const int*)d_in[2];
    const float* eattr  = (const float*)d_in[3];
    const float* hn_h   = (const float*)d_in[4];
    const float* hn_c   = (const float*)d_in[5];
    const float* he_h   = (const float*)d_in[6];
    const float* he_c   = (const float*)d_in[7];
    const float* Wih_n  = (const float*)d_in[8];
    const float* Whh_n  = (const float*)d_in[9];
    const float* bih_n  = (const float*)d_in[10];
    const float* bhh_n  = (const float*)d_in[11];
    const float* Wih_e  = (const float*)d_in[12];
    const float* Whh_e  = (const float*)d_in[13];
    const float* bih_e  = (const float*)d_in[14];
    const float* bhh_e  = (const float*)d_in[15];
    const float* We1    = (const float*)d_in[16];
    const float* be1    = (const float*)d_in[17];
    const float* We2    = (const float*)d_in[18];
    const float* be2    = (const float*)d_in[19];
    const float* Wo1    = (const float*)d_in[20];
    const float* bo1    = (const float*)d_in[21];
    const float* Wo2    = (const float*)d_in[22];
    const float* bo2    = (const float*)d_in[23];
    const float* Wn1    = (const float*)d_in[24];
    const float* bn1    = (const float*)d_in[25];
    const float* Wn2    = (const float*)d_in[26];
    const float* bn2    = (const float*)d_in[27];

    const int* row = ei;
    const int* col = ei + EE;

    float* out = (float*)d_out;
    float* out_y   = out;                        // [N,4]
    float* node_h  = out + (size_t)NN * 4;       // [N,20]
    float* node_c  = out + (size_t)NN * 24;      // [N,20]
    float* edge_h  = out + (size_t)NN * 44;      // [N,8]
    float* edge_c  = out + (size_t)NN * 52;      // [N,8]

    // workspace layout (floats): xu[N*37] | full[N*28] | agg[N*32] | cnt[N] | agg2[N*32]
    float* xu   = (float*)d_ws;
    float* full = xu + (size_t)NN * 37;
    float* agg  = full + (size_t)NN * 28;
    float* cnt  = agg + (size_t)NN * 32;
    float* agg2 = cnt + (size_t)NN;

    // zero the accumulators (agg | cnt | agg2 are contiguous)
    hipMemsetAsync(agg, 0, (size_t)NN * (32 + 1 + 32) * sizeof(float), stream);

    int nb_n = (NN + 255) / 256;
    int nb_e = (EE + 255) / 256;

    node_lstm_k<<<nb_n, 256, 0, stream>>>(x, u, hn_h, hn_c, Wih_n, Whh_n, bih_n, bhh_n,
                                          xu, node_h, node_c);
    edge_mlp_k<37, true><<<nb_e, 256, 0, stream>>>(xu, row, col, eattr,
                                                   We1, be1, We2, be2, agg, cnt);
    edge_lstm_k<<<nb_n, 256, 0, stream>>>(agg, cnt, he_h, he_c, Wih_e, Whh_e, bih_e, bhh_e,
                                          node_h, edge_h, edge_c, full);
    edge_mlp_k<28, false><<<nb_e, 256, 0, stream>>>(full, row, col, eattr,
                                                    Wo1, bo1, Wo2, bo2, agg2, nullptr);
    node_out_k<<<nb_n, 256, 0, stream>>>(full, agg2, cnt, Wn1, bn1, Wn2, bn2, out_y);
}

// Round 2
// 925.443 us; speedup vs baseline: 3.2545x; 3.2545x over previous
//
#include <hip/hip_runtime.h>
#include <math.h>

#define NN 50000
#define EE 800000

__device__ __forceinline__ float sigmoidf_(float x) { return 1.0f / (1.0f + __expf(-x)); }

// ---------------- node history LSTM + xu build ----------------
__global__ __launch_bounds__(256) void node_lstm_k(
    const float* __restrict__ x, const float* __restrict__ u,
    const float* __restrict__ h0, const float* __restrict__ c0,
    const float* __restrict__ Wih, const float* __restrict__ Whh,
    const float* __restrict__ bih, const float* __restrict__ bhh,
    float* __restrict__ xu_out, float* __restrict__ h_out, float* __restrict__ c_out)
{
    __shared__ float sWih[80 * 37];
    __shared__ float sWhh[80 * 20];
    __shared__ float sb[80];
    for (int i = threadIdx.x; i < 80 * 37; i += 256) sWih[i] = Wih[i];
    for (int i = threadIdx.x; i < 80 * 20; i += 256) sWhh[i] = Whh[i];
    if (threadIdx.x < 80) sb[threadIdx.x] = bih[threadIdx.x] + bhh[threadIdx.x];
    __syncthreads();
    int n = blockIdx.x * 256 + threadIdx.x;
    if (n >= NN) return;

    float xu[37];
#pragma unroll
    for (int k = 0; k < 5; k++) xu[k] = x[n * 5 + k];
#pragma unroll
    for (int k = 0; k < 32; k++) xu[5 + k] = u[n * 32 + k];
#pragma unroll
    for (int k = 0; k < 37; k++) xu_out[(size_t)n * 37 + k] = xu[k];

    float h[20];
#pragma unroll
    for (int k = 0; k < 20; k++) h[k] = h0[n * 20 + k];

#pragma unroll 1
    for (int r = 0; r < 20; r++) {
        float gi = sb[r], gf = sb[20 + r], gg = sb[40 + r], go = sb[60 + r];
#pragma unroll
        for (int k = 0; k < 37; k++) {
            float v = xu[k];
            gi = fmaf(v, sWih[r * 37 + k], gi);
            gf = fmaf(v, sWih[(20 + r) * 37 + k], gf);
            gg = fmaf(v, sWih[(40 + r) * 37 + k], gg);
            go = fmaf(v, sWih[(60 + r) * 37 + k], go);
        }
#pragma unroll
        for (int k = 0; k < 20; k++) {
            float v = h[k];
            gi = fmaf(v, sWhh[r * 20 + k], gi);
            gf = fmaf(v, sWhh[(20 + r) * 20 + k], gf);
            gg = fmaf(v, sWhh[(40 + r) * 20 + k], gg);
            go = fmaf(v, sWhh[(60 + r) * 20 + k], go);
        }
        float cr = c0[n * 20 + r];
        float cn = sigmoidf_(gf) * cr + sigmoidf_(gi) * tanhf(gg);
        float hn = sigmoidf_(go) * tanhf(cn);
        h_out[n * 20 + r] = hn;
        c_out[n * 20 + r] = cn;
    }
}

// ---------------- CSR build ----------------
__global__ __launch_bounds__(256) void csr_count_k(const int* __restrict__ col,
                                                   int* __restrict__ count)
{
    int e = blockIdx.x * 256 + threadIdx.x;
    if (e < EE) atomicAdd(&count[col[e]], 1);
}

// single-block exclusive scan over NN counts; also writes float degree
__global__ __launch_bounds__(1024) void scan_k(const int* __restrict__ count,
                                               int* __restrict__ offset,
                                               float* __restrict__ cntf)
{
    __shared__ int part[1024];
    int tid = threadIdx.x;
    const int chunk = (NN + 1023) / 1024;
    int lo = tid * chunk;
    int hi = lo + chunk; if (hi > NN) hi = NN;
    int s = 0;
    for (int i = lo; i < hi; i++) s += count[i];
    part[tid] = s;
    __syncthreads();
    for (int d = 1; d < 1024; d <<= 1) {
        int v = (tid >= d) ? part[tid - d] : 0;
        __syncthreads();
        part[tid] += v;
        __syncthreads();
    }
    int run = (tid == 0) ? 0 : part[tid - 1];
    for (int i = lo; i < hi; i++) {
        offset[i] = run;
        cntf[i] = (float)count[i];
        run += count[i];
    }
}

__global__ __launch_bounds__(256) void csr_fill_k(const int* __restrict__ col,
                                                  const int* __restrict__ offset,
                                                  int* __restrict__ cursor,
                                                  int* __restrict__ eid)
{
    int e = blockIdx.x * 256 + threadIdx.x;
    if (e >= EE) return;
    int c = col[e];
    int pos = atomicAdd(&cursor[c], 1);
    eid[offset[c] + pos] = e;
}

// ---------------- segment sum via gather (32 lanes per node) ----------------
__global__ __launch_bounds__(256) void seg_sum_k(const float* __restrict__ msgs,
                                                 const int* __restrict__ offset,
                                                 const int* __restrict__ count,
                                                 const int* __restrict__ eid,
                                                 float* __restrict__ out)
{
    int n = blockIdx.x * 8 + (threadIdx.x >> 5);
    int f = threadIdx.x & 31;
    if (n >= NN) return;
    int off = offset[n], d = count[n];
    float s = 0.f;
    for (int i = 0; i < d; i++) {
        int e = eid[off + i];
        s += msgs[(size_t)e * 32 + f];
    }
    out[(size_t)n * 32 + f] = s;
}

// ---------------- edge MLP: ATOMIC=true scatters to agg; else stores msgs ----------------
template <int F, bool ATOMIC, bool DO_CNT>
__global__ __launch_bounds__(256) void edge_mlp_k(
    const float* __restrict__ feat,
    const int* __restrict__ row, const int* __restrict__ col,
    const float* __restrict__ eattr,
    const float* __restrict__ W1, const float* __restrict__ b1,
    const float* __restrict__ W2, const float* __restrict__ b2,
    float* __restrict__ dst_buf, float* __restrict__ cnt)
{
    constexpr int IN = 2 * F + 4;
    __shared__ __align__(16) float sW1[IN * 64];
    __shared__ __align__(16) float sW2[64 * 32];
    __shared__ float sb1[64];
    __shared__ float sb2[32];
    for (int i = threadIdx.x; i < IN * 64; i += 256) sW1[i] = W1[i];
    for (int i = threadIdx.x; i < 64 * 32; i += 256) sW2[i] = W2[i];
    if (threadIdx.x < 64) sb1[threadIdx.x] = b1[threadIdx.x];
    if (threadIdx.x < 32) sb2[threadIdx.x] = b2[threadIdx.x];
    __syncthreads();
    int e = blockIdx.x * 256 + threadIdx.x;
    if (e >= EE) return;

    int r = row[e], c = col[e];
    float h[IN];
    const float* fr = &feat[(size_t)r * F];
    const float* fc = &feat[(size_t)c * F];
#pragma unroll
    for (int k = 0; k < F; k++) h[k] = fr[k];
#pragma unroll
    for (int k = 0; k < F; k++) h[F + k] = fc[k];
    float4 ev = *(const float4*)&eattr[(size_t)e * 4];
    h[2 * F] = ev.x; h[2 * F + 1] = ev.y; h[2 * F + 2] = ev.z; h[2 * F + 3] = ev.w;

    float out[32];
#pragma unroll
    for (int m = 0; m < 32; m++) out[m] = sb2[m];

#pragma unroll 1
    for (int j = 0; j < 64; j += 4) {
        float s[4] = {sb1[j], sb1[j + 1], sb1[j + 2], sb1[j + 3]};
#pragma unroll
        for (int k = 0; k < IN; k++) {
            float4 w = *(const float4*)&sW1[k * 64 + j];
            s[0] = fmaf(h[k], w.x, s[0]);
            s[1] = fmaf(h[k], w.y, s[1]);
            s[2] = fmaf(h[k], w.z, s[2]);
            s[3] = fmaf(h[k], w.w, s[3]);
        }
        s[0] = fmaxf(s[0], 0.f); s[1] = fmaxf(s[1], 0.f);
        s[2] = fmaxf(s[2], 0.f); s[3] = fmaxf(s[3], 0.f);
#pragma unroll
        for (int jj = 0; jj < 4; jj++) {
#pragma unroll
            for (int m = 0; m < 32; m += 4) {
                float4 w = *(const float4*)&sW2[(j + jj) * 32 + m];
                out[m]     = fmaf(s[jj], w.x, out[m]);
                out[m + 1] = fmaf(s[jj], w.y, out[m + 1]);
                out[m + 2] = fmaf(s[jj], w.z, out[m + 2]);
                out[m + 3] = fmaf(s[jj], w.w, out[m + 3]);
            }
        }
    }

    if (ATOMIC) {
        float* dst = &dst_buf[(size_t)c * 32];
#pragma unroll
        for (int m = 0; m < 32; m++) atomicAdd(&dst[m], out[m]);
        if (DO_CNT) atomicAdd(&cnt[c], 1.0f);
    } else {
        float* dst = &dst_buf[(size_t)e * 32];
#pragma unroll
        for (int m = 0; m < 32; m += 4) {
            *(float4*)&dst[m] = make_float4(out[m], out[m + 1], out[m + 2], out[m + 3]);
        }
    }
}

// ---------------- edge history LSTM + full build ----------------
__global__ __launch_bounds__(256) void edge_lstm_k(
    const float* __restrict__ agg, const float* __restrict__ cnt,
    const float* __restrict__ h0, const float* __restrict__ c0,
    const float* __restrict__ Wih, const float* __restrict__ Whh,
    const float* __restrict__ bih, const float* __restrict__ bhh,
    const float* __restrict__ node_h,
    float* __restrict__ h_out, float* __restrict__ c_out, float* __restrict__ full)
{
    __shared__ float sWih[32 * 32];
    __shared__ float sWhh[32 * 8];
    __shared__ float sb[32];
    for (int i = threadIdx.x; i < 32 * 32; i += 256) sWih[i] = Wih[i];
    for (int i = threadIdx.x; i < 32 * 8; i += 256) sWhh[i] = Whh[i];
    if (threadIdx.x < 32) sb[threadIdx.x] = bih[threadIdx.x] + bhh[threadIdx.x];
    __syncthreads();
    int n = blockIdx.x * 256 + threadIdx.x;
    if (n >= NN) return;

    float inv = 1.0f / fmaxf(cnt[n], 1.0f);
    float msg[32];
#pragma unroll
    for (int k = 0; k < 32; k++) msg[k] = agg[(size_t)n * 32 + k] * inv;
    float h[8];
#pragma unroll
    for (int k = 0; k < 8; k++) h[k] = h0[n * 8 + k];
    float hn_arr[8];

#pragma unroll
    for (int r = 0; r < 8; r++) {
        float gi = sb[r], gf = sb[8 + r], gg = sb[16 + r], go = sb[24 + r];
#pragma unroll
        for (int k = 0; k < 32; k++) {
            float v = msg[k];
            gi = fmaf(v, sWih[r * 32 + k], gi);
            gf = fmaf(v, sWih[(8 + r) * 32 + k], gf);
            gg = fmaf(v, sWih[(16 + r) * 32 + k], gg);
            go = fmaf(v, sWih[(24 + r) * 32 + k], go);
        }
#pragma unroll
        for (int k = 0; k < 8; k++) {
            float v = h[k];
            gi = fmaf(v, sWhh[r * 8 + k], gi);
            gf = fmaf(v, sWhh[(8 + r) * 8 + k], gf);
            gg = fmaf(v, sWhh[(16 + r) * 8 + k], gg);
            go = fmaf(v, sWhh[(24 + r) * 8 + k], go);
        }
        float cr = c0[n * 8 + r];
        float cn = sigmoidf_(gf) * cr + sigmoidf_(gi) * tanhf(gg);
        float hn = sigmoidf_(go) * tanhf(cn);
        h_out[n * 8 + r] = hn;
        c_out[n * 8 + r] = cn;
        hn_arr[r] = hn;
    }
#pragma unroll
    for (int k = 0; k < 20; k++) full[(size_t)n * 28 + k] = node_h[n * 20 + k];
#pragma unroll
    for (int k = 0; k < 8; k++) full[(size_t)n * 28 + 20 + k] = hn_arr[k];
}

// ---------------- output node MLP ----------------
__global__ __launch_bounds__(256) void node_out_k(
    const float* __restrict__ full, const float* __restrict__ agg2, const float* __restrict__ cnt,
    const float* __restrict__ W1, const float* __restrict__ b1,
    const float* __restrict__ W2, const float* __restrict__ b2,
    float* __restrict__ out)
{
    __shared__ __align__(16) float sW1[60 * 64];
    __shared__ __align__(16) float sW2[64 * 4];
    __shared__ float sb1[64];
    __shared__ float sb2[4];
    for (int i = threadIdx.x; i < 60 * 64; i += 256) sW1[i] = W1[i];
    for (int i = threadIdx.x; i < 64 * 4; i += 256) sW2[i] = W2[i];
    if (threadIdx.x < 64) sb1[threadIdx.x] = b1[threadIdx.x];
    if (threadIdx.x < 4) sb2[threadIdx.x] = b2[threadIdx.x];
    __syncthreads();
    int n = blockIdx.x * 256 + threadIdx.x;
    if (n >= NN) return;

    float in[60];
#pragma unroll
    for (int k = 0; k < 28; k++) in[k] = full[(size_t)n * 28 + k];
    float inv = 1.0f / fmaxf(cnt[n], 1.0f);
#pragma unroll
    for (int k = 0; k < 32; k++) in[28 + k] = agg2[(size_t)n * 32 + k] * inv;

    float o[4] = {sb2[0], sb2[1], sb2[2], sb2[3]};
#pragma unroll 1
    for (int j = 0; j < 64; j += 4) {
        float s[4] = {sb1[j], sb1[j + 1], sb1[j + 2], sb1[j + 3]};
#pragma unroll
        for (int k = 0; k < 60; k++) {
            float4 w = *(const float4*)&sW1[k * 64 + j];
            s[0] = fmaf(in[k], w.x, s[0]);
            s[1] = fmaf(in[k], w.y, s[1]);
            s[2] = fmaf(in[k], w.z, s[2]);
            s[3] = fmaf(in[k], w.w, s[3]);
        }
#pragma unroll
        for (int jj = 0; jj < 4; jj++) {
            float sv = fmaxf(s[jj], 0.0f);
            float4 w = *(const float4*)&sW2[(j + jj) * 4];
            o[0] = fmaf(sv, w.x, o[0]);
            o[1] = fmaf(sv, w.y, o[1]);
            o[2] = fmaf(sv, w.z, o[2]);
            o[3] = fmaf(sv, w.w, o[3]);
        }
    }
#pragma unroll
    for (int m = 0; m < 4; m++) out[n * 4 + m] = o[m];
}

extern "C" void kernel_launch(void* const* d_in, const int* in_sizes, int n_in,
                              void* d_out, int out_size, void* d_ws, size_t ws_size,
                              hipStream_t stream) {
    (void)in_sizes; (void)n_in; (void)out_size;
    const float* x      = (const float*)d_in[0];
    const float* u      = (const float*)d_in[1];
    const int*   ei     = (const int*)d_in[2];
    const float* eattr  = (const float*)d_in[3];
    const float* hn_h   = (const float*)d_in[4];
    const float* hn_c   = (const float*)d_in[5];
    const float* he_h   = (const float*)d_in[6];
    const float* he_c   = (const float*)d_in[7];
    const float* Wih_n  = (const float*)d_in[8];
    const float* Whh_n  = (const float*)d_in[9];
    const float* bih_n  = (const float*)d_in[10];
    const float* bhh_n  = (const float*)d_in[11];
    const float* Wih_e  = (const float*)d_in[12];
    const float* Whh_e  = (const float*)d_in[13];
    const float* bih_e  = (const float*)d_in[14];
    const float* bhh_e  = (const float*)d_in[15];
    const float* We1    = (const float*)d_in[16];
    const float* be1    = (const float*)d_in[17];
    const float* We2    = (const float*)d_in[18];
    const float* be2    = (const float*)d_in[19];
    const float* Wo1    = (const float*)d_in[20];
    const float* bo1    = (const float*)d_in[21];
    const float* Wo2    = (const float*)d_in[22];
    const float* bo2    = (const float*)d_in[23];
    const float* Wn1    = (const float*)d_in[24];
    const float* bn1    = (const float*)d_in[25];
    const float* Wn2    = (const float*)d_in[26];
    const float* bn2    = (const float*)d_in[27];

    const int* row = ei;
    const int* col = ei + EE;

    float* out = (float*)d_out;
    float* out_y   = out;                        // [N,4]
    float* node_h  = out + (size_t)NN * 4;       // [N,20]
    float* node_c  = out + (size_t)NN * 24;      // [N,20]
    float* edge_h  = out + (size_t)NN * 44;      // [N,8]
    float* edge_c  = out + (size_t)NN * 52;      // [N,8]

    int nb_n = (NN + 255) / 256;
    int nb_e = (EE + 255) / 256;

    // ---- fast path workspace layout (floats) ----
    // xu[N*37] | full[N*28] | agg[N*32] | cntf[N] | agg2[N*32] |
    // count[N](int) | cursor[N](int) | offset[N](int) | eid[E](int) | msgs[E*32]
    float* xu   = (float*)d_ws;
    float* full = xu + (size_t)NN * 37;
    float* agg  = full + (size_t)NN * 28;
    float* cntf = agg + (size_t)NN * 32;
    float* agg2 = cntf + (size_t)NN;
    int*   count  = (int*)(agg2 + (size_t)NN * 32);
    int*   cursor = count + NN;
    int*   offset = cursor + NN;
    int*   eid    = offset + NN;
    float* msgs   = (float*)(eid + EE);
    size_t needed = ((size_t)(msgs - xu) + (size_t)EE * 32) * sizeof(float);

    if (ws_size >= needed) {
        // ---- fast path: CSR gather, no fp32 atomics ----
        hipMemsetAsync(count, 0, 2 * (size_t)NN * sizeof(int), stream);  // count + cursor

        node_lstm_k<<<nb_n, 256, 0, stream>>>(x, u, hn_h, hn_c, Wih_n, Whh_n, bih_n, bhh_n,
                                              xu, node_h, node_c);
        csr_count_k<<<nb_e, 256, 0, stream>>>(col, count);
        scan_k<<<1, 1024, 0, stream>>>(count, offset, cntf);
        csr_fill_k<<<nb_e, 256, 0, stream>>>(col, offset, cursor, eid);

        edge_mlp_k<37, false, false><<<nb_e, 256, 0, stream>>>(xu, row, col, eattr,
                                                               We1, be1, We2, be2, msgs, nullptr);
        seg_sum_k<<<(NN + 7) / 8, 256, 0, stream>>>(msgs, offset, count, eid, agg);
        edge_lstm_k<<<nb_n, 256, 0, stream>>>(agg, cntf, he_h, he_c, Wih_e, Whh_e, bih_e, bhh_e,
                                              node_h, edge_h, edge_c, full);
        edge_mlp_k<28, false, false><<<nb_e, 256, 0, stream>>>(full, row, col, eattr,
                                                               Wo1, bo1, Wo2, bo2, msgs, nullptr);
        seg_sum_k<<<(NN + 7) / 8, 256, 0, stream>>>(msgs, offset, count, eid, agg2);
        node_out_k<<<nb_n, 256, 0, stream>>>(full, agg2, cntf, Wn1, bn1, Wn2, bn2, out_y);
    } else {
        // ---- fallback: atomic scatter (round-1 behavior) ----
        hipMemsetAsync(agg, 0, (size_t)NN * (32 + 1 + 32) * sizeof(float), stream);
        node_lstm_k<<<nb_n, 256, 0, stream>>>(x, u, hn_h, hn_c, Wih_n, Whh_n, bih_n, bhh_n,
                                              xu, node_h, node_c);
        edge_mlp_k<37, true, true><<<nb_e, 256, 0, stream>>>(xu, row, col, eattr,
                                                             We1, be1, We2, be2, agg, cntf);
        edge_lstm_k<<<nb_n, 256, 0, stream>>>(agg, cntf, he_h, he_c, Wih_e, Whh_e, bih_e, bhh_e,
                                              node_h, edge_h, edge_c, full);
        edge_mlp_k<28, true, false><<<nb_e, 256, 0, stream>>>(full, row, col, eattr,
                                                              Wo1, bo1, Wo2, bo2, agg2, nullptr);
        node_out_k<<<nb_n, 256, 0, stream>>>(full, agg2, cntf, Wn1, bn1, Wn2, bn2, out_y);
    }
}

// Round 3
// 512.747 us; speedup vs baseline: 5.8740x; 1.8049x over previous
//
#include <hip/hip_runtime.h>
#include <math.h>

#define NN 50000
#define EE 800000

typedef short bf16x8 __attribute__((ext_vector_type(8)));
typedef float f32x4 __attribute__((ext_vector_type(4)));
#define MFMA16(a, b, c) __builtin_amdgcn_mfma_f32_16x16x32_bf16(a, b, c, 0, 0, 0)

__device__ __forceinline__ float sigmoidf_(float x) { return 1.0f / (1.0f + __expf(-x)); }

__device__ __forceinline__ unsigned short f2bf(float f) {
    unsigned u = __builtin_bit_cast(unsigned, f);
    u += 0x7FFFu + ((u >> 16) & 1u);
    return (unsigned short)(u >> 16);
}

// ---------------- node history LSTM + xu build ----------------
__global__ __launch_bounds__(256) void node_lstm_k(
    const float* __restrict__ x, const float* __restrict__ u,
    const float* __restrict__ h0, const float* __restrict__ c0,
    const float* __restrict__ Wih, const float* __restrict__ Whh,
    const float* __restrict__ bih, const float* __restrict__ bhh,
    float* __restrict__ xu_out, float* __restrict__ h_out, float* __restrict__ c_out)
{
    __shared__ float sWih[80 * 37];
    __shared__ float sWhh[80 * 20];
    __shared__ float sb[80];
    for (int i = threadIdx.x; i < 80 * 37; i += 256) sWih[i] = Wih[i];
    for (int i = threadIdx.x; i < 80 * 20; i += 256) sWhh[i] = Whh[i];
    if (threadIdx.x < 80) sb[threadIdx.x] = bih[threadIdx.x] + bhh[threadIdx.x];
    __syncthreads();
    int n = blockIdx.x * 256 + threadIdx.x;
    if (n >= NN) return;

    float xu[37];
#pragma unroll
    for (int k = 0; k < 5; k++) xu[k] = x[n * 5 + k];
#pragma unroll
    for (int k = 0; k < 32; k++) xu[5 + k] = u[n * 32 + k];
#pragma unroll
    for (int k = 0; k < 37; k++) xu_out[(size_t)n * 37 + k] = xu[k];

    float h[20];
#pragma unroll
    for (int k = 0; k < 20; k++) h[k] = h0[n * 20 + k];

#pragma unroll 1
    for (int r = 0; r < 20; r++) {
        float gi = sb[r], gf = sb[20 + r], gg = sb[40 + r], go = sb[60 + r];
#pragma unroll
        for (int k = 0; k < 37; k++) {
            float v = xu[k];
            gi = fmaf(v, sWih[r * 37 + k], gi);
            gf = fmaf(v, sWih[(20 + r) * 37 + k], gf);
            gg = fmaf(v, sWih[(40 + r) * 37 + k], gg);
            go = fmaf(v, sWih[(60 + r) * 37 + k], go);
        }
#pragma unroll
        for (int k = 0; k < 20; k++) {
            float v = h[k];
            gi = fmaf(v, sWhh[r * 20 + k], gi);
            gf = fmaf(v, sWhh[(20 + r) * 20 + k], gf);
            gg = fmaf(v, sWhh[(40 + r) * 20 + k], gg);
            go = fmaf(v, sWhh[(60 + r) * 20 + k], go);
        }
        float cr = c0[n * 20 + r];
        float cn = sigmoidf_(gf) * cr + sigmoidf_(gi) * tanhf(gg);
        float hn = sigmoidf_(go) * tanhf(cn);
        h_out[n * 20 + r] = hn;
        c_out[n * 20 + r] = cn;
    }
}

// ---------------- CSR build ----------------
__global__ __launch_bounds__(256) void csr_count_k(const int* __restrict__ col,
                                                   int* __restrict__ count)
{
    int e = blockIdx.x * 256 + threadIdx.x;
    if (e < EE) atomicAdd(&count[col[e]], 1);
}

__global__ __launch_bounds__(1024) void scan_k(const int* __restrict__ count,
                                               int* __restrict__ offset,
                                               float* __restrict__ cntf)
{
    __shared__ int part[1024];
    int tid = threadIdx.x;
    const int chunk = (NN + 1023) / 1024;
    int lo = tid * chunk;
    int hi = lo + chunk; if (hi > NN) hi = NN;
    int s = 0;
    for (int i = lo; i < hi; i++) s += count[i];
    part[tid] = s;
    __syncthreads();
    for (int d = 1; d < 1024; d <<= 1) {
        int v = (tid >= d) ? part[tid - d] : 0;
        __syncthreads();
        part[tid] += v;
        __syncthreads();
    }
    int run = (tid == 0) ? 0 : part[tid - 1];
    for (int i = lo; i < hi; i++) {
        offset[i] = run;
        cntf[i] = (float)count[i];
        run += count[i];
    }
}

// fill CSR: also emit slot-ordered row/col/eid so the MFMA kernel reads
// coalesced and msgs lands in CSR order (seg-sum becomes streaming).
__global__ __launch_bounds__(256) void csr_fill2_k(const int* __restrict__ row,
                                                   const int* __restrict__ col,
                                                   const int* __restrict__ offset,
                                                   int* __restrict__ cursor,
                                                   int* __restrict__ eidp,
                                                   int* __restrict__ rowp,
                                                   int* __restrict__ colp)
{
    int e = blockIdx.x * 256 + threadIdx.x;
    if (e >= EE) return;
    int c = col[e];
    int pos = atomicAdd(&cursor[c], 1);
    int slot = offset[c] + pos;
    eidp[slot] = e;
    rowp[slot] = row[e];
    colp[slot] = c;
}

// ---------------- segment sum over CSR-ordered msgs (coalesced) ----------------
__global__ __launch_bounds__(256) void seg_sum2_k(const float* __restrict__ msgs,
                                                  const int* __restrict__ offset,
                                                  const int* __restrict__ count,
                                                  float* __restrict__ out)
{
    int n = blockIdx.x * 8 + (threadIdx.x >> 5);
    int f = threadIdx.x & 31;
    if (n >= NN) return;
    size_t off = (size_t)offset[n];
    int d = count[n];
    float s = 0.f;
    for (int i = 0; i < d; i++) s += msgs[(off + i) * 32 + f];
    out[(size_t)n * 32 + f] = s;
}

// ---------------- fused 2-layer edge MLP via bf16 MFMA ----------------
// Processes edges in CSR-slot order. Per block: 256 edges, 4 waves x 64 edges
// (4 M-tiles of 16). Layer1: [16x INK] x [INK x 64]; Layer2: relu -> [16x64] x [64x32].
// F = per-node feature width (37 or 28); IN = 2F+4 actual; INK = K padded to x32.
template <int F, int INK>
__global__ __launch_bounds__(256) void edge_mlp_mfma_k(
    const float* __restrict__ feat,
    const int* __restrict__ rowp, const int* __restrict__ colp, const int* __restrict__ eidp,
    const float* __restrict__ eattr,
    const float* __restrict__ W1, const float* __restrict__ b1,
    const float* __restrict__ W2, const float* __restrict__ b2,
    float* __restrict__ msgs)
{
    constexpr int IN = 2 * F + 4;
    constexpr int S1 = INK / 32;
    constexpr int W1ST = INK + 8;   // bf16 units; x2 bytes -> multiple of 16B
    constexpr int C1ST = 72;        // 144 B rows

    __shared__ __align__(16) unsigned short sW1[64][W1ST];   // [outcol n][k]
    __shared__ __align__(16) unsigned short sW2[32][C1ST];   // [outcol n][k]
    __shared__ __align__(16) unsigned short sC1[4][64][C1ST];// per-wave [edge][hid]
    __shared__ float sb1[64], sb2[32];

    const int tid = threadIdx.x;
    // zero W1 (covers K padding)
    for (int i = tid; i < 64 * W1ST; i += 256) ((unsigned short*)sW1)[i] = 0;
    __syncthreads();
    for (int i = tid; i < IN * 64; i += 256) {
        int k = i >> 6, n = i & 63;
        sW1[n][k] = f2bf(W1[i]);
    }
    for (int i = tid; i < 64 * 32; i += 256) {
        int k = i >> 5, n = i & 31;
        sW2[n][k] = f2bf(W2[i]);
    }
    if (tid < 64) sb1[tid] = b1[tid];
    if (tid < 32) sb2[tid] = b2[tid];
    __syncthreads();

    const int wave = tid >> 6;
    const int lane = tid & 63;
    const int lr = lane & 15;      // M-row / N-col within a 16-tile
    const int jb = lane >> 4;      // k-subblock 0..3
    const size_t slotBase = (size_t)blockIdx.x * 256 + (size_t)wave * 64;

    int rN[4], cN[4], eO[4];
#pragma unroll
    for (int m = 0; m < 4; m++) {
        size_t s = slotBase + m * 16 + lr;
        rN[m] = rowp[s];
        cN[m] = colp[s];
        eO[m] = eidp[s];
    }

    // ---- layer 1 ----
    f32x4 acc1[4][4] = {};  // [m][n]
#pragma unroll
    for (int s = 0; s < S1; s++) {
        bf16x8 bfr[4];
#pragma unroll
        for (int n = 0; n < 4; n++)
            bfr[n] = *(const bf16x8*)&sW1[n * 16 + lr][s * 32 + jb * 8];
        const int kbase = s * 32 + jb * 8;
#pragma unroll
        for (int m = 0; m < 4; m++) {
            float v[8];
#pragma unroll
            for (int j = 0; j < 8; j++) {
                int kk = kbase + j;
                float xv;
                if (kk < F)            xv = feat[(size_t)rN[m] * F + kk];
                else if (kk < 2 * F)   xv = feat[(size_t)cN[m] * F + (kk - F)];
                else if (kk < IN)      xv = eattr[(size_t)eO[m] * 4 + (kk - 2 * F)];
                else                   xv = 0.f;
                v[j] = xv;
            }
            bf16x8 afr;
#pragma unroll
            for (int j = 0; j < 8; j++) afr[j] = (short)f2bf(v[j]);
#pragma unroll
            for (int n = 0; n < 4; n++)
                acc1[m][n] = MFMA16(afr, bfr[n], acc1[m][n]);
        }
    }

    // ---- bias + relu -> bf16 -> wave-private LDS [64 edges][64 hid] ----
    unsigned short (*myC1)[C1ST] = sC1[wave];
#pragma unroll
    for (int m = 0; m < 4; m++) {
#pragma unroll
        for (int n = 0; n < 4; n++) {
            float bb = sb1[n * 16 + lr];
#pragma unroll
            for (int r4 = 0; r4 < 4; r4++) {
                float vv = fmaxf(acc1[m][n][r4] + bb, 0.f);
                myC1[m * 16 + jb * 4 + r4][n * 16 + lr] = f2bf(vv);
            }
        }
    }

    // ---- layer 2: [64x64] x [64x32] ----
    f32x4 acc2[4][2] = {};
#pragma unroll
    for (int s = 0; s < 2; s++) {
        bf16x8 bfr2[2];
#pragma unroll
        for (int n = 0; n < 2; n++)
            bfr2[n] = *(const bf16x8*)&sW2[n * 16 + lr][s * 32 + jb * 8];
#pragma unroll
        for (int m = 0; m < 4; m++) {
            bf16x8 afr = *(const bf16x8*)&myC1[m * 16 + lr][s * 32 + jb * 8];
            acc2[m][0] = MFMA16(afr, bfr2[0], acc2[m][0]);
            acc2[m][1] = MFMA16(afr, bfr2[1], acc2[m][1]);
        }
    }

    // ---- epilogue: bias + store fp32 msgs in CSR-slot order ----
#pragma unroll
    for (int m = 0; m < 4; m++) {
#pragma unroll
        for (int n = 0; n < 2; n++) {
            float bb = sb2[n * 16 + lr];
#pragma unroll
            for (int r4 = 0; r4 < 4; r4++) {
                size_t slot = slotBase + m * 16 + jb * 4 + r4;
                msgs[slot * 32 + n * 16 + lr] = acc2[m][n][r4] + bb;
            }
        }
    }
}

// ---------------- edge history LSTM + full build ----------------
__global__ __launch_bounds__(256) void edge_lstm_k(
    const float* __restrict__ agg, const float* __restrict__ cnt,
    const float* __restrict__ h0, const float* __restrict__ c0,
    const float* __restrict__ Wih, const float* __restrict__ Whh,
    const float* __restrict__ bih, const float* __restrict__ bhh,
    const float* __restrict__ node_h,
    float* __restrict__ h_out, float* __restrict__ c_out, float* __restrict__ full)
{
    __shared__ float sWih[32 * 32];
    __shared__ float sWhh[32 * 8];
    __shared__ float sb[32];
    for (int i = threadIdx.x; i < 32 * 32; i += 256) sWih[i] = Wih[i];
    for (int i = threadIdx.x; i < 32 * 8; i += 256) sWhh[i] = Whh[i];
    if (threadIdx.x < 32) sb[threadIdx.x] = bih[threadIdx.x] + bhh[threadIdx.x];
    __syncthreads();
    int n = blockIdx.x * 256 + threadIdx.x;
    if (n >= NN) return;

    float inv = 1.0f / fmaxf(cnt[n], 1.0f);
    float msg[32];
#pragma unroll
    for (int k = 0; k < 32; k++) msg[k] = agg[(size_t)n * 32 + k] * inv;
    float h[8];
#pragma unroll
    for (int k = 0; k < 8; k++) h[k] = h0[n * 8 + k];
    float hn_arr[8];

#pragma unroll
    for (int r = 0; r < 8; r++) {
        float gi = sb[r], gf = sb[8 + r], gg = sb[16 + r], go = sb[24 + r];
#pragma unroll
        for (int k = 0; k < 32; k++) {
            float v = msg[k];
            gi = fmaf(v, sWih[r * 32 + k], gi);
            gf = fmaf(v, sWih[(8 + r) * 32 + k], gf);
            gg = fmaf(v, sWih[(16 + r) * 32 + k], gg);
            go = fmaf(v, sWih[(24 + r) * 32 + k], go);
        }
#pragma unroll
        for (int k = 0; k < 8; k++) {
            float v = h[k];
            gi = fmaf(v, sWhh[r * 8 + k], gi);
            gf = fmaf(v, sWhh[(8 + r) * 8 + k], gf);
            gg = fmaf(v, sWhh[(16 + r) * 8 + k], gg);
            go = fmaf(v, sWhh[(24 + r) * 8 + k], go);
        }
        float cr = c0[n * 8 + r];
        float cn = sigmoidf_(gf) * cr + sigmoidf_(gi) * tanhf(gg);
        float hn = sigmoidf_(go) * tanhf(cn);
        h_out[n * 8 + r] = hn;
        c_out[n * 8 + r] = cn;
        hn_arr[r] = hn;
    }
#pragma unroll
    for (int k = 0; k < 20; k++) full[(size_t)n * 28 + k] = node_h[n * 20 + k];
#pragma unroll
    for (int k = 0; k < 8; k++) full[(size_t)n * 28 + 20 + k] = hn_arr[k];
}

// ---------------- output node MLP ----------------
__global__ __launch_bounds__(256) void node_out_k(
    const float* __restrict__ full, const float* __restrict__ agg2, const float* __restrict__ cnt,
    const float* __restrict__ W1, const float* __restrict__ b1,
    const float* __restrict__ W2, const float* __restrict__ b2,
    float* __restrict__ out)
{
    __shared__ __align__(16) float sW1[60 * 64];
    __shared__ __align__(16) float sW2[64 * 4];
    __shared__ float sb1[64];
    __shared__ float sb2[4];
    for (int i = threadIdx.x; i < 60 * 64; i += 256) sW1[i] = W1[i];
    for (int i = threadIdx.x; i < 64 * 4; i += 256) sW2[i] = W2[i];
    if (threadIdx.x < 64) sb1[threadIdx.x] = b1[threadIdx.x];
    if (threadIdx.x < 4) sb2[threadIdx.x] = b2[threadIdx.x];
    __syncthreads();
    int n = blockIdx.x * 256 + threadIdx.x;
    if (n >= NN) return;

    float in[60];
#pragma unroll
    for (int k = 0; k < 28; k++) in[k] = full[(size_t)n * 28 + k];
    float inv = 1.0f / fmaxf(cnt[n], 1.0f);
#pragma unroll
    for (int k = 0; k < 32; k++) in[28 + k] = agg2[(size_t)n * 32 + k] * inv;

    float o[4] = {sb2[0], sb2[1], sb2[2], sb2[3]};
#pragma unroll 1
    for (int j = 0; j < 64; j += 4) {
        float s[4] = {sb1[j], sb1[j + 1], sb1[j + 2], sb1[j + 3]};
#pragma unroll
        for (int k = 0; k < 60; k++) {
            float4 w = *(const float4*)&sW1[k * 64 + j];
            s[0] = fmaf(in[k], w.x, s[0]);
            s[1] = fmaf(in[k], w.y, s[1]);
            s[2] = fmaf(in[k], w.z, s[2]);
            s[3] = fmaf(in[k], w.w, s[3]);
        }
#pragma unroll
        for (int jj = 0; jj < 4; jj++) {
            float sv = fmaxf(s[jj], 0.0f);
            float4 w = *(const float4*)&sW2[(j + jj) * 4];
            o[0] = fmaf(sv, w.x, o[0]);
            o[1] = fmaf(sv, w.y, o[1]);
            o[2] = fmaf(sv, w.z, o[2]);
            o[3] = fmaf(sv, w.w, o[3]);
        }
    }
#pragma unroll
    for (int m = 0; m < 4; m++) out[n * 4 + m] = o[m];
}

// ---------------- fallback atomic edge MLP (round-1 path) ----------------
template <int F, bool DO_CNT>
__global__ __launch_bounds__(256) void edge_mlp_atomic_k(
    const float* __restrict__ feat,
    const int* __restrict__ row, const int* __restrict__ col,
    const float* __restrict__ eattr,
    const float* __restrict__ W1, const float* __restrict__ b1,
    const float* __restrict__ W2, const float* __restrict__ b2,
    float* __restrict__ agg, float* __restrict__ cnt)
{
    constexpr int IN = 2 * F + 4;
    __shared__ __align__(16) float sW1[IN * 64];
    __shared__ __align__(16) float sW2[64 * 32];
    __shared__ float sb1[64];
    __shared__ float sb2[32];
    for (int i = threadIdx.x; i < IN * 64; i += 256) sW1[i] = W1[i];
    for (int i = threadIdx.x; i < 64 * 32; i += 256) sW2[i] = W2[i];
    if (threadIdx.x < 64) sb1[threadIdx.x] = b1[threadIdx.x];
    if (threadIdx.x < 32) sb2[threadIdx.x] = b2[threadIdx.x];
    __syncthreads();
    int e = blockIdx.x * 256 + threadIdx.x;
    if (e >= EE) return;

    int r = row[e], c = col[e];
    float h[IN];
#pragma unroll
    for (int k = 0; k < F; k++) h[k] = feat[(size_t)r * F + k];
#pragma unroll
    for (int k = 0; k < F; k++) h[F + k] = feat[(size_t)c * F + k];
    float4 ev = *(const float4*)&eattr[(size_t)e * 4];
    h[2 * F] = ev.x; h[2 * F + 1] = ev.y; h[2 * F + 2] = ev.z; h[2 * F + 3] = ev.w;

    float out[32];
#pragma unroll
    for (int m = 0; m < 32; m++) out[m] = sb2[m];
#pragma unroll 1
    for (int j = 0; j < 64; j += 4) {
        float s[4] = {sb1[j], sb1[j + 1], sb1[j + 2], sb1[j + 3]};
#pragma unroll
        for (int k = 0; k < IN; k++) {
            float4 w = *(const float4*)&sW1[k * 64 + j];
            s[0] = fmaf(h[k], w.x, s[0]);
            s[1] = fmaf(h[k], w.y, s[1]);
            s[2] = fmaf(h[k], w.z, s[2]);
            s[3] = fmaf(h[k], w.w, s[3]);
        }
        s[0] = fmaxf(s[0], 0.f); s[1] = fmaxf(s[1], 0.f);
        s[2] = fmaxf(s[2], 0.f); s[3] = fmaxf(s[3], 0.f);
#pragma unroll
        for (int jj = 0; jj < 4; jj++) {
#pragma unroll
            for (int m = 0; m < 32; m += 4) {
                float4 w = *(const float4*)&sW2[(j + jj) * 32 + m];
                out[m]     = fmaf(s[jj], w.x, out[m]);
                out[m + 1] = fmaf(s[jj], w.y, out[m + 1]);
                out[m + 2] = fmaf(s[jj], w.z, out[m + 2]);
                out[m + 3] = fmaf(s[jj], w.w, out[m + 3]);
            }
        }
    }
    float* dst = &agg[(size_t)c * 32];
#pragma unroll
    for (int m = 0; m < 32; m++) atomicAdd(&dst[m], out[m]);
    if (DO_CNT) atomicAdd(&cnt[c], 1.0f);
}

extern "C" void kernel_launch(void* const* d_in, const int* in_sizes, int n_in,
                              void* d_out, int out_size, void* d_ws, size_t ws_size,
                              hipStream_t stream) {
    (void)in_sizes; (void)n_in; (void)out_size;
    const float* x      = (const float*)d_in[0];
    const float* u      = (const float*)d_in[1];
    const int*   ei     = (const int*)d_in[2];
    const float* eattr  = (const float*)d_in[3];
    const float* hn_h   = (const float*)d_in[4];
    const float* hn_c   = (const float*)d_in[5];
    const float* he_h   = (const float*)d_in[6];
    const float* he_c   = (const float*)d_in[7];
    const float* Wih_n  = (const float*)d_in[8];
    const float* Whh_n  = (const float*)d_in[9];
    const float* bih_n  = (const float*)d_in[10];
    const float* bhh_n  = (const float*)d_in[11];
    const float* Wih_e  = (const float*)d_in[12];
    const float* Whh_e  = (const float*)d_in[13];
    const float* bih_e  = (const float*)d_in[14];
    const float* bhh_e  = (const float*)d_in[15];
    const float* We1    = (const float*)d_in[16];
    const float* be1    = (const float*)d_in[17];
    const float* We2    = (const float*)d_in[18];
    const float* be2    = (const float*)d_in[19];
    const float* Wo1    = (const float*)d_in[20];
    const float* bo1    = (const float*)d_in[21];
    const float* Wo2    = (const float*)d_in[22];
    const float* bo2    = (const float*)d_in[23];
    const float* Wn1    = (const float*)d_in[24];
    const float* bn1    = (const float*)d_in[25];
    const float* Wn2    = (const float*)d_in[26];
    const float* bn2    = (const float*)d_in[27];

    const int* row = ei;
    const int* col = ei + EE;

    float* out = (float*)d_out;
    float* out_y   = out;                        // [N,4]
    float* node_h  = out + (size_t)NN * 4;       // [N,20]
    float* node_c  = out + (size_t)NN * 24;      // [N,20]
    float* edge_h  = out + (size_t)NN * 44;      // [N,8]
    float* edge_c  = out + (size_t)NN * 52;      // [N,8]

    int nb_n = (NN + 255) / 256;
    int nb_e = (EE + 255) / 256;

    // ws layout (floats):
    // xu[N*37] | full[N*28] | agg[N*32] | cntf[N] | agg2[N*32] |
    // count[N] cursor[N] offset[N] (int) | eidp[E] rowp[E] colp[E] (int) | msgs[E*32]
    float* xu   = (float*)d_ws;
    float* full = xu + (size_t)NN * 37;
    float* agg  = full + (size_t)NN * 28;
    float* cntf = agg + (size_t)NN * 32;
    float* agg2 = cntf + (size_t)NN;
    int*   count  = (int*)(agg2 + (size_t)NN * 32);
    int*   cursor = count + NN;
    int*   offset = cursor + NN;
    int*   eidp   = offset + NN;
    int*   rowp   = eidp + EE;
    int*   colp   = rowp + EE;
    float* msgs   = (float*)(colp + EE);
    size_t needed = ((size_t)((float*)(colp + EE) - xu) + (size_t)EE * 32) * sizeof(float);

    if (ws_size >= needed) {
        hipMemsetAsync(count, 0, 2 * (size_t)NN * sizeof(int), stream);  // count + cursor

        node_lstm_k<<<nb_n, 256, 0, stream>>>(x, u, hn_h, hn_c, Wih_n, Whh_n, bih_n, bhh_n,
                                              xu, node_h, node_c);
        csr_count_k<<<nb_e, 256, 0, stream>>>(col, count);
        scan_k<<<1, 1024, 0, stream>>>(count, offset, cntf);
        csr_fill2_k<<<nb_e, 256, 0, stream>>>(row, col, offset, cursor, eidp, rowp, colp);

        edge_mlp_mfma_k<37, 96><<<EE / 256, 256, 0, stream>>>(
            xu, rowp, colp, eidp, eattr, We1, be1, We2, be2, msgs);
        seg_sum2_k<<<(NN + 7) / 8, 256, 0, stream>>>(msgs, offset, count, agg);
        edge_lstm_k<<<nb_n, 256, 0, stream>>>(agg, cntf, he_h, he_c, Wih_e, Whh_e, bih_e, bhh_e,
                                              node_h, edge_h, edge_c, full);
        edge_mlp_mfma_k<28, 64><<<EE / 256, 256, 0, stream>>>(
            full, rowp, colp, eidp, eattr, Wo1, bo1, Wo2, bo2, msgs);
        seg_sum2_k<<<(NN + 7) / 8, 256, 0, stream>>>(msgs, offset, count, agg2);
        node_out_k<<<nb_n, 256, 0, stream>>>(full, agg2, cntf, Wn1, bn1, Wn2, bn2, out_y);
    } else {
        // fallback: atomic scatter path
        hipMemsetAsync(agg, 0, (size_t)NN * (32 + 1 + 32) * sizeof(float), stream);
        node_lstm_k<<<nb_n, 256, 0, stream>>>(x, u, hn_h, hn_c, Wih_n, Whh_n, bih_n, bhh_n,
                                              xu, node_h, node_c);
        edge_mlp_atomic_k<37, true><<<nb_e, 256, 0, stream>>>(xu, row, col, eattr,
                                                              We1, be1, We2, be2, agg, cntf);
        edge_lstm_k<<<nb_n, 256, 0, stream>>>(agg, cntf, he_h, he_c, Wih_e, Whh_e, bih_e, bhh_e,
                                              node_h, edge_h, edge_c, full);
        edge_mlp_atomic_k<28, false><<<nb_e, 256, 0, stream>>>(full, row, col, eattr,
                                                               Wo1, bo1, Wo2, bo2, agg2, nullptr);
        node_out_k<<<nb_n, 256, 0, stream>>>(full, agg2, cntf, Wn1, bn1, Wn2, bn2, out_y);
    }
}

// Round 4
// 418.481 us; speedup vs baseline: 7.1971x; 1.2253x over previous
//
#include <hip/hip_runtime.h>
#include <math.h>

#define NN 50000
#define EE 800000
#define SBLK ((NN + 255) / 256)   // 196 scan blocks

typedef short bf16x8 __attribute__((ext_vector_type(8)));
typedef float f32x4 __attribute__((ext_vector_type(4)));
#define MFMA16(a, b, c) __builtin_amdgcn_mfma_f32_16x16x32_bf16(a, b, c, 0, 0, 0)

__device__ __forceinline__ float sigmoidf_(float x) { return 1.0f / (1.0f + __expf(-x)); }

__device__ __forceinline__ unsigned short f2bf(float f) {
    unsigned u = __builtin_bit_cast(unsigned, f);
    u += 0x7FFFu + ((u >> 16) & 1u);
    return (unsigned short)(u >> 16);
}

// ---------------- node history LSTM + xu build ----------------
__global__ __launch_bounds__(256) void node_lstm_k(
    const float* __restrict__ x, const float* __restrict__ u,
    const float* __restrict__ h0, const float* __restrict__ c0,
    const float* __restrict__ Wih, const float* __restrict__ Whh,
    const float* __restrict__ bih, const float* __restrict__ bhh,
    float* __restrict__ xu_out, float* __restrict__ h_out, float* __restrict__ c_out)
{
    __shared__ float sWih[80 * 37];
    __shared__ float sWhh[80 * 20];
    __shared__ float sb[80];
    for (int i = threadIdx.x; i < 80 * 37; i += 256) sWih[i] = Wih[i];
    for (int i = threadIdx.x; i < 80 * 20; i += 256) sWhh[i] = Whh[i];
    if (threadIdx.x < 80) sb[threadIdx.x] = bih[threadIdx.x] + bhh[threadIdx.x];
    __syncthreads();
    int n = blockIdx.x * 256 + threadIdx.x;
    if (n >= NN) return;

    float xu[37];
#pragma unroll
    for (int k = 0; k < 5; k++) xu[k] = x[n * 5 + k];
#pragma unroll
    for (int k = 0; k < 32; k++) xu[5 + k] = u[n * 32 + k];
#pragma unroll
    for (int k = 0; k < 37; k++) xu_out[(size_t)n * 37 + k] = xu[k];

    float h[20];
#pragma unroll
    for (int k = 0; k < 20; k++) h[k] = h0[n * 20 + k];

#pragma unroll 1
    for (int r = 0; r < 20; r++) {
        float gi = sb[r], gf = sb[20 + r], gg = sb[40 + r], go = sb[60 + r];
#pragma unroll
        for (int k = 0; k < 37; k++) {
            float v = xu[k];
            gi = fmaf(v, sWih[r * 37 + k], gi);
            gf = fmaf(v, sWih[(20 + r) * 37 + k], gf);
            gg = fmaf(v, sWih[(40 + r) * 37 + k], gg);
            go = fmaf(v, sWih[(60 + r) * 37 + k], go);
        }
#pragma unroll
        for (int k = 0; k < 20; k++) {
            float v = h[k];
            gi = fmaf(v, sWhh[r * 20 + k], gi);
            gf = fmaf(v, sWhh[(20 + r) * 20 + k], gf);
            gg = fmaf(v, sWhh[(40 + r) * 20 + k], gg);
            go = fmaf(v, sWhh[(60 + r) * 20 + k], go);
        }
        float cr = c0[n * 20 + r];
        float cn = sigmoidf_(gf) * cr + sigmoidf_(gi) * tanhf(gg);
        float hn = sigmoidf_(go) * tanhf(cn);
        h_out[n * 20 + r] = hn;
        c_out[n * 20 + r] = cn;
    }
}

// ---------------- CSR build ----------------
__global__ __launch_bounds__(256) void csr_count_k(const int* __restrict__ col,
                                                   int* __restrict__ count)
{
    int e = blockIdx.x * 256 + threadIdx.x;
    if (e < EE) atomicAdd(&count[col[e]], 1);
}

// ---- parallel 3-level exclusive scan over count[NN] ----
__global__ __launch_bounds__(256) void scan1_k(const int* __restrict__ count,
                                               int* __restrict__ bsum)
{
    __shared__ int red[256];
    int t = threadIdx.x;
    int i = blockIdx.x * 256 + t;
    red[t] = (i < NN) ? count[i] : 0;
    __syncthreads();
#pragma unroll
    for (int d = 128; d > 0; d >>= 1) {
        if (t < d) red[t] += red[t + d];
        __syncthreads();
    }
    if (t == 0) bsum[blockIdx.x] = red[0];
}

__global__ __launch_bounds__(256) void scan2_k(const int* __restrict__ bsum,
                                               int* __restrict__ bpre)
{
    __shared__ int s[256];
    int t = threadIdx.x;
    int v = (t < SBLK) ? bsum[t] : 0;
    s[t] = v;
    __syncthreads();
#pragma unroll
    for (int d = 1; d < 256; d <<= 1) {
        int w = (t >= d) ? s[t - d] : 0;
        __syncthreads();
        s[t] += w;
        __syncthreads();
    }
    if (t < SBLK) bpre[t] = s[t] - v;   // exclusive prefix of block sums
}

__global__ __launch_bounds__(256) void scan3_k(const int* __restrict__ count,
                                               const int* __restrict__ bpre,
                                               int* __restrict__ offset,
                                               float* __restrict__ cntf)
{
    __shared__ int s[256];
    int t = threadIdx.x;
    int i = blockIdx.x * 256 + t;
    int v = (i < NN) ? count[i] : 0;
    s[t] = v;
    __syncthreads();
#pragma unroll
    for (int d = 1; d < 256; d <<= 1) {
        int w = (t >= d) ? s[t - d] : 0;
        __syncthreads();
        s[t] += w;
        __syncthreads();
    }
    if (i < NN) {
        offset[i] = bpre[blockIdx.x] + s[t] - v;   // exclusive
        cntf[i] = (float)v;
    }
}

// fill CSR: emit slot-ordered row/col/eid so the MFMA kernel reads coalesced
// and msgs lands in CSR order (seg-sum becomes streaming).
__global__ __launch_bounds__(256) void csr_fill2_k(const int* __restrict__ row,
                                                   const int* __restrict__ col,
                                                   const int* __restrict__ offset,
                                                   int* __restrict__ cursor,
                                                   int* __restrict__ eidp,
                                                   int* __restrict__ rowp,
                                                   int* __restrict__ colp)
{
    int e = blockIdx.x * 256 + threadIdx.x;
    if (e >= EE) return;
    int c = col[e];
    int pos = atomicAdd(&cursor[c], 1);
    int slot = offset[c] + pos;
    eidp[slot] = e;
    rowp[slot] = row[e];
    colp[slot] = c;
}

// ---------------- segment sum over CSR-ordered msgs (coalesced) ----------------
__global__ __launch_bounds__(256) void seg_sum2_k(const float* __restrict__ msgs,
                                                  const int* __restrict__ offset,
                                                  const int* __restrict__ count,
                                                  float* __restrict__ out)
{
    int n = blockIdx.x * 8 + (threadIdx.x >> 5);
    int f = threadIdx.x & 31;
    if (n >= NN) return;
    size_t off = (size_t)offset[n];
    int d = count[n];
    float s = 0.f;
    for (int i = 0; i < d; i++) s += msgs[(off + i) * 32 + f];
    out[(size_t)n * 32 + f] = s;
}

// ---------------- fused 2-layer edge MLP via bf16 MFMA ----------------
template <int F, int INK>
__global__ __launch_bounds__(256) void edge_mlp_mfma_k(
    const float* __restrict__ feat,
    const int* __restrict__ rowp, const int* __restrict__ colp, const int* __restrict__ eidp,
    const float* __restrict__ eattr,
    const float* __restrict__ W1, const float* __restrict__ b1,
    const float* __restrict__ W2, const float* __restrict__ b2,
    float* __restrict__ msgs)
{
    constexpr int IN = 2 * F + 4;
    constexpr int S1 = INK / 32;
    constexpr int W1ST = INK + 8;
    constexpr int C1ST = 72;

    __shared__ __align__(16) unsigned short sW1[64][W1ST];
    __shared__ __align__(16) unsigned short sW2[32][C1ST];
    __shared__ __align__(16) unsigned short sC1[4][64][C1ST];
    __shared__ float sb1[64], sb2[32];

    const int tid = threadIdx.x;
    for (int i = tid; i < 64 * W1ST; i += 256) ((unsigned short*)sW1)[i] = 0;
    __syncthreads();
    for (int i = tid; i < IN * 64; i += 256) {
        int k = i >> 6, n = i & 63;
        sW1[n][k] = f2bf(W1[i]);
    }
    for (int i = tid; i < 64 * 32; i += 256) {
        int k = i >> 5, n = i & 31;
        sW2[n][k] = f2bf(W2[i]);
    }
    if (tid < 64) sb1[tid] = b1[tid];
    if (tid < 32) sb2[tid] = b2[tid];
    __syncthreads();

    const int wave = tid >> 6;
    const int lane = tid & 63;
    const int lr = lane & 15;
    const int jb = lane >> 4;
    const size_t slotBase = (size_t)blockIdx.x * 256 + (size_t)wave * 64;

    int rN[4], cN[4], eO[4];
#pragma unroll
    for (int m = 0; m < 4; m++) {
        size_t s = slotBase + m * 16 + lr;
        rN[m] = rowp[s];
        cN[m] = colp[s];
        eO[m] = eidp[s];
    }

    // ---- layer 1 ----
    f32x4 acc1[4][4] = {};
#pragma unroll
    for (int s = 0; s < S1; s++) {
        bf16x8 bfr[4];
#pragma unroll
        for (int n = 0; n < 4; n++)
            bfr[n] = *(const bf16x8*)&sW1[n * 16 + lr][s * 32 + jb * 8];
        const int kbase = s * 32 + jb * 8;
#pragma unroll
        for (int m = 0; m < 4; m++) {
            float v[8];
#pragma unroll
            for (int j = 0; j < 8; j++) {
                int kk = kbase + j;
                float xv;
                if (kk < F)            xv = feat[(size_t)rN[m] * F + kk];
                else if (kk < 2 * F)   xv = feat[(size_t)cN[m] * F + (kk - F)];
                else if (kk < IN)      xv = eattr[(size_t)eO[m] * 4 + (kk - 2 * F)];
                else                   xv = 0.f;
                v[j] = xv;
            }
            bf16x8 afr;
#pragma unroll
            for (int j = 0; j < 8; j++) afr[j] = (short)f2bf(v[j]);
#pragma unroll
            for (int n = 0; n < 4; n++)
                acc1[m][n] = MFMA16(afr, bfr[n], acc1[m][n]);
        }
    }

    // ---- bias + relu -> bf16 -> wave-private LDS ----
    unsigned short (*myC1)[C1ST] = sC1[wave];
#pragma unroll
    for (int m = 0; m < 4; m++) {
#pragma unroll
        for (int n = 0; n < 4; n++) {
            float bb = sb1[n * 16 + lr];
#pragma unroll
            for (int r4 = 0; r4 < 4; r4++) {
                float vv = fmaxf(acc1[m][n][r4] + bb, 0.f);
                myC1[m * 16 + jb * 4 + r4][n * 16 + lr] = f2bf(vv);
            }
        }
    }

    // ---- layer 2 ----
    f32x4 acc2[4][2] = {};
#pragma unroll
    for (int s = 0; s < 2; s++) {
        bf16x8 bfr2[2];
#pragma unroll
        for (int n = 0; n < 2; n++)
            bfr2[n] = *(const bf16x8*)&sW2[n * 16 + lr][s * 32 + jb * 8];
#pragma unroll
        for (int m = 0; m < 4; m++) {
            bf16x8 afr = *(const bf16x8*)&myC1[m * 16 + lr][s * 32 + jb * 8];
            acc2[m][0] = MFMA16(afr, bfr2[0], acc2[m][0]);
            acc2[m][1] = MFMA16(afr, bfr2[1], acc2[m][1]);
        }
    }

    // ---- epilogue ----
#pragma unroll
    for (int m = 0; m < 4; m++) {
#pragma unroll
        for (int n = 0; n < 2; n++) {
            float bb = sb2[n * 16 + lr];
#pragma unroll
            for (int r4 = 0; r4 < 4; r4++) {
                size_t slot = slotBase + m * 16 + jb * 4 + r4;
                msgs[slot * 32 + n * 16 + lr] = acc2[m][n][r4] + bb;
            }
        }
    }
}

// ---------------- edge history LSTM + full build ----------------
__global__ __launch_bounds__(256) void edge_lstm_k(
    const float* __restrict__ agg, const float* __restrict__ cnt,
    const float* __restrict__ h0, const float* __restrict__ c0,
    const float* __restrict__ Wih, const float* __restrict__ Whh,
    const float* __restrict__ bih, const float* __restrict__ bhh,
    const float* __restrict__ node_h,
    float* __restrict__ h_out, float* __restrict__ c_out, float* __restrict__ full)
{
    __shared__ float sWih[32 * 32];
    __shared__ float sWhh[32 * 8];
    __shared__ float sb[32];
    for (int i = threadIdx.x; i < 32 * 32; i += 256) sWih[i] = Wih[i];
    for (int i = threadIdx.x; i < 32 * 8; i += 256) sWhh[i] = Whh[i];
    if (threadIdx.x < 32) sb[threadIdx.x] = bih[threadIdx.x] + bhh[threadIdx.x];
    __syncthreads();
    int n = blockIdx.x * 256 + threadIdx.x;
    if (n >= NN) return;

    float inv = 1.0f / fmaxf(cnt[n], 1.0f);
    float msg[32];
#pragma unroll
    for (int k = 0; k < 32; k++) msg[k] = agg[(size_t)n * 32 + k] * inv;
    float h[8];
#pragma unroll
    for (int k = 0; k < 8; k++) h[k] = h0[n * 8 + k];
    float hn_arr[8];

#pragma unroll
    for (int r = 0; r < 8; r++) {
        float gi = sb[r], gf = sb[8 + r], gg = sb[16 + r], go = sb[24 + r];
#pragma unroll
        for (int k = 0; k < 32; k++) {
            float v = msg[k];
            gi = fmaf(v, sWih[r * 32 + k], gi);
            gf = fmaf(v, sWih[(8 + r) * 32 + k], gf);
            gg = fmaf(v, sWih[(16 + r) * 32 + k], gg);
            go = fmaf(v, sWih[(24 + r) * 32 + k], go);
        }
#pragma unroll
        for (int k = 0; k < 8; k++) {
            float v = h[k];
            gi = fmaf(v, sWhh[r * 8 + k], gi);
            gf = fmaf(v, sWhh[(8 + r) * 8 + k], gf);
            gg = fmaf(v, sWhh[(16 + r) * 8 + k], gg);
            go = fmaf(v, sWhh[(24 + r) * 8 + k], go);
        }
        float cr = c0[n * 8 + r];
        float cn = sigmoidf_(gf) * cr + sigmoidf_(gi) * tanhf(gg);
        float hn = sigmoidf_(go) * tanhf(cn);
        h_out[n * 8 + r] = hn;
        c_out[n * 8 + r] = cn;
        hn_arr[r] = hn;
    }
#pragma unroll
    for (int k = 0; k < 20; k++) full[(size_t)n * 28 + k] = node_h[n * 20 + k];
#pragma unroll
    for (int k = 0; k < 8; k++) full[(size_t)n * 28 + 20 + k] = hn_arr[k];
}

// ---------------- output node MLP ----------------
__global__ __launch_bounds__(256) void node_out_k(
    const float* __restrict__ full, const float* __restrict__ agg2, const float* __restrict__ cnt,
    const float* __restrict__ W1, const float* __restrict__ b1,
    const float* __restrict__ W2, const float* __restrict__ b2,
    float* __restrict__ out)
{
    __shared__ __align__(16) float sW1[60 * 64];
    __shared__ __align__(16) float sW2[64 * 4];
    __shared__ float sb1[64];
    __shared__ float sb2[4];
    for (int i = threadIdx.x; i < 60 * 64; i += 256) sW1[i] = W1[i];
    for (int i = threadIdx.x; i < 64 * 4; i += 256) sW2[i] = W2[i];
    if (threadIdx.x < 64) sb1[threadIdx.x] = b1[threadIdx.x];
    if (threadIdx.x < 4) sb2[threadIdx.x] = b2[threadIdx.x];
    __syncthreads();
    int n = blockIdx.x * 256 + threadIdx.x;
    if (n >= NN) return;

    float in[60];
#pragma unroll
    for (int k = 0; k < 28; k++) in[k] = full[(size_t)n * 28 + k];
    float inv = 1.0f / fmaxf(cnt[n], 1.0f);
#pragma unroll
    for (int k = 0; k < 32; k++) in[28 + k] = agg2[(size_t)n * 32 + k] * inv;

    float o[4] = {sb2[0], sb2[1], sb2[2], sb2[3]};
#pragma unroll 1
    for (int j = 0; j < 64; j += 4) {
        float s[4] = {sb1[j], sb1[j + 1], sb1[j + 2], sb1[j + 3]};
#pragma unroll
        for (int k = 0; k < 60; k++) {
            float4 w = *(const float4*)&sW1[k * 64 + j];
            s[0] = fmaf(in[k], w.x, s[0]);
            s[1] = fmaf(in[k], w.y, s[1]);
            s[2] = fmaf(in[k], w.z, s[2]);
            s[3] = fmaf(in[k], w.w, s[3]);
        }
#pragma unroll
        for (int jj = 0; jj < 4; jj++) {
            float sv = fmaxf(s[jj], 0.0f);
            float4 w = *(const float4*)&sW2[(j + jj) * 4];
            o[0] = fmaf(sv, w.x, o[0]);
            o[1] = fmaf(sv, w.y, o[1]);
            o[2] = fmaf(sv, w.z, o[2]);
            o[3] = fmaf(sv, w.w, o[3]);
        }
    }
#pragma unroll
    for (int m = 0; m < 4; m++) out[n * 4 + m] = o[m];
}

// ---------------- fallback atomic edge MLP ----------------
template <int F, bool DO_CNT>
__global__ __launch_bounds__(256) void edge_mlp_atomic_k(
    const float* __restrict__ feat,
    const int* __restrict__ row, const int* __restrict__ col,
    const float* __restrict__ eattr,
    const float* __restrict__ W1, const float* __restrict__ b1,
    const float* __restrict__ W2, const float* __restrict__ b2,
    float* __restrict__ agg, float* __restrict__ cnt)
{
    constexpr int IN = 2 * F + 4;
    __shared__ __align__(16) float sW1[IN * 64];
    __shared__ __align__(16) float sW2[64 * 32];
    __shared__ float sb1[64];
    __shared__ float sb2[32];
    for (int i = threadIdx.x; i < IN * 64; i += 256) sW1[i] = W1[i];
    for (int i = threadIdx.x; i < 64 * 32; i += 256) sW2[i] = W2[i];
    if (threadIdx.x < 64) sb1[threadIdx.x] = b1[threadIdx.x];
    if (threadIdx.x < 32) sb2[threadIdx.x] = b2[threadIdx.x];
    __syncthreads();
    int e = blockIdx.x * 256 + threadIdx.x;
    if (e >= EE) return;

    int r = row[e], c = col[e];
    float h[IN];
#pragma unroll
    for (int k = 0; k < F; k++) h[k] = feat[(size_t)r * F + k];
#pragma unroll
    for (int k = 0; k < F; k++) h[F + k] = feat[(size_t)c * F + k];
    float4 ev = *(const float4*)&eattr[(size_t)e * 4];
    h[2 * F] = ev.x; h[2 * F + 1] = ev.y; h[2 * F + 2] = ev.z; h[2 * F + 3] = ev.w;

    float out[32];
#pragma unroll
    for (int m = 0; m < 32; m++) out[m] = sb2[m];
#pragma unroll 1
    for (int j = 0; j < 64; j += 4) {
        float s[4] = {sb1[j], sb1[j + 1], sb1[j + 2], sb1[j + 3]};
#pragma unroll
        for (int k = 0; k < IN; k++) {
            float4 w = *(const float4*)&sW1[k * 64 + j];
            s[0] = fmaf(h[k], w.x, s[0]);
            s[1] = fmaf(h[k], w.y, s[1]);
            s[2] = fmaf(h[k], w.z, s[2]);
            s[3] = fmaf(h[k], w.w, s[3]);
        }
        s[0] = fmaxf(s[0], 0.f); s[1] = fmaxf(s[1], 0.f);
        s[2] = fmaxf(s[2], 0.f); s[3] = fmaxf(s[3], 0.f);
#pragma unroll
        for (int jj = 0; jj < 4; jj++) {
#pragma unroll
            for (int m = 0; m < 32; m += 4) {
                float4 w = *(const float4*)&sW2[(j + jj) * 32 + m];
                out[m]     = fmaf(s[jj], w.x, out[m]);
                out[m + 1] = fmaf(s[jj], w.y, out[m + 1]);
                out[m + 2] = fmaf(s[jj], w.z, out[m + 2]);
                out[m + 3] = fmaf(s[jj], w.w, out[m + 3]);
            }
        }
    }
    float* dst = &agg[(size_t)c * 32];
#pragma unroll
    for (int m = 0; m < 32; m++) atomicAdd(&dst[m], out[m]);
    if (DO_CNT) atomicAdd(&cnt[c], 1.0f);
}

extern "C" void kernel_launch(void* const* d_in, const int* in_sizes, int n_in,
                              void* d_out, int out_size, void* d_ws, size_t ws_size,
                              hipStream_t stream) {
    (void)in_sizes; (void)n_in; (void)out_size;
    const float* x      = (const float*)d_in[0];
    const float* u      = (const float*)d_in[1];
    const int*   ei     = (const int*)d_in[2];
    const float* eattr  = (const float*)d_in[3];
    const float* hn_h   = (const float*)d_in[4];
    const float* hn_c   = (const float*)d_in[5];
    const float* he_h   = (const float*)d_in[6];
    const float* he_c   = (const float*)d_in[7];
    const float* Wih_n  = (const float*)d_in[8];
    const float* Whh_n  = (const float*)d_in[9];
    const float* bih_n  = (const float*)d_in[10];
    const float* bhh_n  = (const float*)d_in[11];
    const float* Wih_e  = (const float*)d_in[12];
    const float* Whh_e  = (const float*)d_in[13];
    const float* bih_e  = (const float*)d_in[14];
    const float* bhh_e  = (const float*)d_in[15];
    const float* We1    = (const float*)d_in[16];
    const float* be1    = (const float*)d_in[17];
    const float* We2    = (const float*)d_in[18];
    const float* be2    = (const float*)d_in[19];
    const float* Wo1    = (const float*)d_in[20];
    const float* bo1    = (const float*)d_in[21];
    const float* Wo2    = (const float*)d_in[22];
    const float* bo2    = (const float*)d_in[23];
    const float* Wn1    = (const float*)d_in[24];
    const float* bn1    = (const float*)d_in[25];
    const float* Wn2    = (const float*)d_in[26];
    const float* bn2    = (const float*)d_in[27];

    const int* row = ei;
    const int* col = ei + EE;

    float* out = (float*)d_out;
    float* out_y   = out;                        // [N,4]
    float* node_h  = out + (size_t)NN * 4;       // [N,20]
    float* node_c  = out + (size_t)NN * 24;      // [N,20]
    float* edge_h  = out + (size_t)NN * 44;      // [N,8]
    float* edge_c  = out + (size_t)NN * 52;      // [N,8]

    int nb_n = (NN + 255) / 256;
    int nb_e = (EE + 255) / 256;

    // ws layout (floats):
    // xu[N*37] | full[N*28] | agg[N*32] | cntf[N] | agg2[N*32] |
    // count[N] cursor[N] offset[N] bsum[SBLK] bpre[SBLK] (int) |
    // eidp[E] rowp[E] colp[E] (int) | msgs[E*32]
    float* xu   = (float*)d_ws;
    float* full = xu + (size_t)NN * 37;
    float* agg  = full + (size_t)NN * 28;
    float* cntf = agg + (size_t)NN * 32;
    float* agg2 = cntf + (size_t)NN;
    int*   count  = (int*)(agg2 + (size_t)NN * 32);
    int*   cursor = count + NN;
    int*   offset = cursor + NN;
    int*   bsum   = offset + NN;
    int*   bpre   = bsum + SBLK;
    int*   eidp   = bpre + SBLK;
    int*   rowp   = eidp + EE;
    int*   colp   = rowp + EE;
    float* msgs   = (float*)(colp + EE);
    size_t needed = ((size_t)((float*)(colp + EE) - xu) + (size_t)EE * 32) * sizeof(float);

    if (ws_size >= needed) {
        hipMemsetAsync(count, 0, 2 * (size_t)NN * sizeof(int), stream);  // count + cursor

        node_lstm_k<<<nb_n, 256, 0, stream>>>(x, u, hn_h, hn_c, Wih_n, Whh_n, bih_n, bhh_n,
                                              xu, node_h, node_c);
        csr_count_k<<<nb_e, 256, 0, stream>>>(col, count);
        scan1_k<<<SBLK, 256, 0, stream>>>(count, bsum);
        scan2_k<<<1, 256, 0, stream>>>(bsum, bpre);
        scan3_k<<<SBLK, 256, 0, stream>>>(count, bpre, offset, cntf);
        csr_fill2_k<<<nb_e, 256, 0, stream>>>(row, col, offset, cursor, eidp, rowp, colp);

        edge_mlp_mfma_k<37, 96><<<EE / 256, 256, 0, stream>>>(
            xu, rowp, colp, eidp, eattr, We1, be1, We2, be2, msgs);
        seg_sum2_k<<<(NN + 7) / 8, 256, 0, stream>>>(msgs, offset, count, agg);
        edge_lstm_k<<<nb_n, 256, 0, stream>>>(agg, cntf, he_h, he_c, Wih_e, Whh_e, bih_e, bhh_e,
                                              node_h, edge_h, edge_c, full);
        edge_mlp_mfma_k<28, 64><<<EE / 256, 256, 0, stream>>>(
            full, rowp, colp, eidp, eattr, Wo1, bo1, Wo2, bo2, msgs);
        seg_sum2_k<<<(NN + 7) / 8, 256, 0, stream>>>(msgs, offset, count, agg2);
        node_out_k<<<nb_n, 256, 0, stream>>>(full, agg2, cntf, Wn1, bn1, Wn2, bn2, out_y);
    } else {
        // fallback: atomic scatter path
        hipMemsetAsync(agg, 0, (size_t)NN * (32 + 1 + 32) * sizeof(float), stream);
        node_lstm_k<<<nb_n, 256, 0, stream>>>(x, u, hn_h, hn_c, Wih_n, Whh_n, bih_n, bhh_n,
                                              xu, node_h, node_c);
        edge_mlp_atomic_k<37, true><<<nb_e, 256, 0, stream>>>(xu, row, col, eattr,
                                                              We1, be1, We2, be2, agg, cntf);
        edge_lstm_k<<<nb_n, 256, 0, stream>>>(agg, cntf, he_h, he_c, Wih_e, Whh_e, bih_e, bhh_e,
                                              node_h, edge_h, edge_c, full);
        edge_mlp_atomic_k<28, false><<<nb_e, 256, 0, stream>>>(full, row, col, eattr,
                                                               Wo1, bo1, Wo2, bo2, agg2, nullptr);
        node_out_k<<<nb_n, 256, 0, stream>>>(full, agg2, cntf, Wn1, bn1, Wn2, bn2, out_y);
    }
}

// Round 5
// 349.440 us; speedup vs baseline: 8.6191x; 1.1976x over previous
//
#include <hip/hip_runtime.h>
#include <math.h>

#define NN 50000
#define EE 800000
#define SBLK ((NN + 255) / 256)   // 196 scan blocks

typedef short bf16x8 __attribute__((ext_vector_type(8)));
typedef float f32x4 __attribute__((ext_vector_type(4)));
typedef unsigned short ushort_t;
#define MFMA16(a, b, c) __builtin_amdgcn_mfma_f32_16x16x32_bf16(a, b, c, 0, 0, 0)

__device__ __forceinline__ float sigmoidf_(float x) { return 1.0f / (1.0f + __expf(-x)); }

__device__ __forceinline__ unsigned short f2bf(float f) {
    unsigned u = __builtin_bit_cast(unsigned, f);
    u += 0x7FFFu + ((u >> 16) & 1u);
    return (unsigned short)(u >> 16);
}
__device__ __forceinline__ float bf2f(unsigned short v) {
    unsigned u = (unsigned)v << 16;
    return __builtin_bit_cast(float, u);
}
__device__ __forceinline__ unsigned pk2(float a, float b) {
    return ((unsigned)f2bf(b) << 16) | (unsigned)f2bf(a);
}

// ---------------- node history LSTM + bf16 padded xu table ----------------
__global__ __launch_bounds__(256) void node_lstm_k(
    const float* __restrict__ x, const float* __restrict__ u,
    const float* __restrict__ h0, const float* __restrict__ c0,
    const float* __restrict__ Wih, const float* __restrict__ Whh,
    const float* __restrict__ bih, const float* __restrict__ bhh,
    ushort_t* __restrict__ xu16, float* __restrict__ h_out, float* __restrict__ c_out)
{
    __shared__ float sWih[80 * 37];
    __shared__ float sWhh[80 * 20];
    __shared__ float sb[80];
    for (int i = threadIdx.x; i < 80 * 37; i += 256) sWih[i] = Wih[i];
    for (int i = threadIdx.x; i < 80 * 20; i += 256) sWhh[i] = Whh[i];
    if (threadIdx.x < 80) sb[threadIdx.x] = bih[threadIdx.x] + bhh[threadIdx.x];
    __syncthreads();
    int n = blockIdx.x * 256 + threadIdx.x;
    if (n >= NN) return;

    float xu[40];
#pragma unroll
    for (int k = 0; k < 5; k++) xu[k] = x[n * 5 + k];
#pragma unroll
    for (int k = 0; k < 32; k++) xu[5 + k] = u[n * 32 + k];
    xu[37] = 0.f; xu[38] = 0.f; xu[39] = 0.f;

    // write bf16 padded row [40] as 5 x uint4
    {
        unsigned w[20];
#pragma unroll
        for (int k = 0; k < 20; k++) w[k] = pk2(xu[2 * k], xu[2 * k + 1]);
        uint4* dst = (uint4*)(xu16 + (size_t)n * 40);
#pragma unroll
        for (int q = 0; q < 5; q++)
            dst[q] = make_uint4(w[q * 4], w[q * 4 + 1], w[q * 4 + 2], w[q * 4 + 3]);
    }

    float h[20];
#pragma unroll
    for (int k = 0; k < 20; k++) h[k] = h0[n * 20 + k];

#pragma unroll 1
    for (int r = 0; r < 20; r++) {
        float gi = sb[r], gf = sb[20 + r], gg = sb[40 + r], go = sb[60 + r];
#pragma unroll
        for (int k = 0; k < 37; k++) {
            float v = xu[k];
            gi = fmaf(v, sWih[r * 37 + k], gi);
            gf = fmaf(v, sWih[(20 + r) * 37 + k], gf);
            gg = fmaf(v, sWih[(40 + r) * 37 + k], gg);
            go = fmaf(v, sWih[(60 + r) * 37 + k], go);
        }
#pragma unroll
        for (int k = 0; k < 20; k++) {
            float v = h[k];
            gi = fmaf(v, sWhh[r * 20 + k], gi);
            gf = fmaf(v, sWhh[(20 + r) * 20 + k], gf);
            gg = fmaf(v, sWhh[(40 + r) * 20 + k], gg);
            go = fmaf(v, sWhh[(60 + r) * 20 + k], go);
        }
        float cr = c0[n * 20 + r];
        float cn = sigmoidf_(gf) * cr + sigmoidf_(gi) * tanhf(gg);
        float hn = sigmoidf_(go) * tanhf(cn);
        h_out[n * 20 + r] = hn;
        c_out[n * 20 + r] = cn;
    }
}

// ---------------- CSR build ----------------
__global__ __launch_bounds__(256) void csr_count_k(const int* __restrict__ col,
                                                   int* __restrict__ count)
{
    int e = blockIdx.x * 256 + threadIdx.x;
    if (e < EE) atomicAdd(&count[col[e]], 1);
}

__global__ __launch_bounds__(256) void scan1_k(const int* __restrict__ count,
                                               int* __restrict__ bsum)
{
    __shared__ int red[256];
    int t = threadIdx.x;
    int i = blockIdx.x * 256 + t;
    red[t] = (i < NN) ? count[i] : 0;
    __syncthreads();
#pragma unroll
    for (int d = 128; d > 0; d >>= 1) {
        if (t < d) red[t] += red[t + d];
        __syncthreads();
    }
    if (t == 0) bsum[blockIdx.x] = red[0];
}

__global__ __launch_bounds__(256) void scan2_k(const int* __restrict__ bsum,
                                               int* __restrict__ bpre)
{
    __shared__ int s[256];
    int t = threadIdx.x;
    int v = (t < SBLK) ? bsum[t] : 0;
    s[t] = v;
    __syncthreads();
#pragma unroll
    for (int d = 1; d < 256; d <<= 1) {
        int w = (t >= d) ? s[t - d] : 0;
        __syncthreads();
        s[t] += w;
        __syncthreads();
    }
    if (t < SBLK) bpre[t] = s[t] - v;
}

__global__ __launch_bounds__(256) void scan3_k(const int* __restrict__ count,
                                               const int* __restrict__ bpre,
                                               int* __restrict__ offset,
                                               float* __restrict__ cntf)
{
    __shared__ int s[256];
    int t = threadIdx.x;
    int i = blockIdx.x * 256 + t;
    int v = (i < NN) ? count[i] : 0;
    s[t] = v;
    __syncthreads();
#pragma unroll
    for (int d = 1; d < 256; d <<= 1) {
        int w = (t >= d) ? s[t - d] : 0;
        __syncthreads();
        s[t] += w;
        __syncthreads();
    }
    if (i < NN) {
        offset[i] = bpre[blockIdx.x] + s[t] - v;
        cntf[i] = (float)v;
    }
}

// fill CSR: slot-ordered row/col + slot-ordered bf16 eattr
__global__ __launch_bounds__(256) void csr_fill3_k(const int* __restrict__ row,
                                                   const int* __restrict__ col,
                                                   const float* __restrict__ eattr,
                                                   const int* __restrict__ offset,
                                                   int* __restrict__ cursor,
                                                   int* __restrict__ rowp,
                                                   int* __restrict__ colp,
                                                   ushort_t* __restrict__ eap)
{
    int e = blockIdx.x * 256 + threadIdx.x;
    if (e >= EE) return;
    int c = col[e];
    int pos = atomicAdd(&cursor[c], 1);
    int slot = offset[c] + pos;
    rowp[slot] = row[e];
    colp[slot] = c;
    float4 ev = *(const float4*)&eattr[(size_t)e * 4];
    uint2 pk = make_uint2(pk2(ev.x, ev.y), pk2(ev.z, ev.w));
    *(uint2*)&eap[(size_t)slot * 4] = pk;
}

// ---------------- segment sum over CSR-ordered msgs (coalesced) ----------------
__global__ __launch_bounds__(256) void seg_sum2_k(const float* __restrict__ msgs,
                                                  const int* __restrict__ offset,
                                                  const int* __restrict__ count,
                                                  float* __restrict__ out)
{
    int n = blockIdx.x * 8 + (threadIdx.x >> 5);
    int f = threadIdx.x & 31;
    if (n >= NN) return;
    size_t off = (size_t)offset[n];
    int d = count[n];
    float s = 0.f;
    for (int i = 0; i < d; i++) s += msgs[(off + i) * 32 + f];
    out[(size_t)n * 32 + f] = s;
}

// ---------------- fused 2-layer edge MLP via bf16 MFMA, v2 ----------------
// feat: bf16 padded table stride STRIDE, K-layout per edge row:
//   F=37: [row40 | col40 | eattr4 | 12 zero]  (INK=96)
//   F=28: [row32 | col28 | eattr4]            (INK=64)
// Layer1 computes D1[hid][edge] (operands swapped) so the accumulator regs are
// hid-adjacent -> packed b64 stores of relu'd bf16 C1. Layer2 standard.
template <int F, int STRIDE, int INK>
__global__ __launch_bounds__(256, 4) void edge_mlp_mfma2_k(
    const ushort_t* __restrict__ feat,
    const int* __restrict__ rowp, const int* __restrict__ colp,
    const ushort_t* __restrict__ eap,
    const float* __restrict__ W1, const float* __restrict__ b1,
    const float* __restrict__ W2, const float* __restrict__ b2,
    float* __restrict__ msgs)
{
    constexpr int S1 = INK / 32;
    constexpr int W1ST = INK + 8;
    constexpr int C1ST = 72;
    __shared__ __align__(16) ushort_t sW1[64][W1ST];
    __shared__ __align__(16) ushort_t sW2[32][C1ST];
    __shared__ __align__(16) ushort_t sC1[4][32][C1ST];

    const int tid = threadIdx.x;
    // stage W1 with K-remap to the gather layout (pad rows zeroed)
    for (int i = tid; i < 64 * INK; i += 256) {
        int nk = i >> 6, n = i & 63;
        int kp = 0; bool z = false;
        if (F == 37) {
            if (nk < 37) kp = nk;
            else if (nk < 40) z = true;
            else if (nk < 77) kp = nk - 3;
            else if (nk < 80) z = true;
            else if (nk < 84) kp = nk - 6;
            else z = true;
        } else {
            if (nk < 28) kp = nk;
            else if (nk < 32) z = true;
            else kp = nk - 4;
        }
        sW1[n][nk] = z ? (ushort_t)0 : f2bf(W1[kp * 64 + n]);
    }
    for (int i = tid; i < 64 * 32; i += 256) {
        int k = i >> 5, n = i & 31;
        sW2[n][k] = f2bf(W2[k * 32 + n]);
    }
    __syncthreads();

    const int wave = tid >> 6, lane = tid & 63;
    const int lr = lane & 15, jb = lane >> 4;
    const size_t slotBase = (size_t)blockIdx.x * 256 + (size_t)wave * 64;
    const float4* b1v = (const float4*)b1;
    ushort_t (*myC1)[C1ST] = sC1[wave];
    const float bb2_0 = b2[lr], bb2_1 = b2[16 + lr];

#pragma unroll
    for (int half = 0; half < 2; half++) {
        // gather B-fragments (2 ne-tiles x S1 chunks), each one aligned 16B load
        bf16x8 xf[2][S1];
#pragma unroll
        for (int ne2 = 0; ne2 < 2; ne2++) {
            size_t slot = slotBase + (size_t)(half * 2 + ne2) * 16 + lr;
            const ushort_t* xr = feat + (size_t)rowp[slot] * STRIDE;
            const ushort_t* xc = feat + (size_t)colp[slot] * STRIDE;
            const ushort_t* ea = eap + slot * 4;
            xf[ne2][0] = *(const bf16x8*)(xr + jb * 8);
            if (F == 37) {
                const ushort_t* p1 = (jb == 0) ? (xr + 32) : (xc + (jb - 1) * 8);
                xf[ne2][1] = *(const bf16x8*)p1;
                const ushort_t* p2 = (jb == 0) ? (xc + 24) : ((jb == 1) ? (xc + 32) : ea);
                bf16x8 v = *(const bf16x8*)p2;
                if (jb >= 2) { v[4] = 0; v[5] = 0; v[6] = 0; v[7] = 0; }
                if (jb == 3) { v[0] = 0; v[1] = 0; v[2] = 0; v[3] = 0; }
                xf[ne2][2] = v;
            } else {
                const ushort_t* pl = (jb < 3) ? (xc + jb * 8) : (xc + 24);
                uint2 lo = *(const uint2*)pl;
                const ushort_t* ph = (jb < 3) ? (pl + 4) : ea;
                uint2 hi = *(const uint2*)ph;
                uint4 cc = make_uint4(lo.x, lo.y, hi.x, hi.y);
                xf[ne2][1] = __builtin_bit_cast(bf16x8, cc);
            }
        }

        // layer 1: D1[hid][edge], bias in C-init
        f32x4 acc1[4][2];
#pragma unroll
        for (int mh = 0; mh < 4; mh++) {
            float4 bv = b1v[mh * 4 + jb];
            f32x4 bi = {bv.x, bv.y, bv.z, bv.w};
            acc1[mh][0] = bi; acc1[mh][1] = bi;
        }
#pragma unroll
        for (int s = 0; s < S1; s++) {
#pragma unroll
            for (int mh = 0; mh < 4; mh++) {
                bf16x8 wf = *(const bf16x8*)&sW1[mh * 16 + lr][s * 32 + jb * 8];
                acc1[mh][0] = MFMA16(wf, xf[0][s], acc1[mh][0]);
                acc1[mh][1] = MFMA16(wf, xf[1][s], acc1[mh][1]);
            }
        }

        // relu -> bf16 -> packed b64 stores into wave-private C1 [edge32][hid72]
#pragma unroll
        for (int mh = 0; mh < 4; mh++) {
#pragma unroll
            for (int ne2 = 0; ne2 < 2; ne2++) {
                f32x4 a = acc1[mh][ne2];
                unsigned w0 = pk2(fmaxf(a[0], 0.f), fmaxf(a[1], 0.f));
                unsigned w1 = pk2(fmaxf(a[2], 0.f), fmaxf(a[3], 0.f));
                *(uint2*)&myC1[ne2 * 16 + lr][mh * 16 + jb * 4] = make_uint2(w0, w1);
            }
        }

        // layer 2: D2[edge][hid2], bias in C-init
        f32x4 acc2[2][2];
#pragma unroll
        for (int m = 0; m < 2; m++) {
            acc2[m][0] = f32x4{bb2_0, bb2_0, bb2_0, bb2_0};
            acc2[m][1] = f32x4{bb2_1, bb2_1, bb2_1, bb2_1};
        }
#pragma unroll
        for (int s2 = 0; s2 < 2; s2++) {
            bf16x8 w2f0 = *(const bf16x8*)&sW2[lr][s2 * 32 + jb * 8];
            bf16x8 w2f1 = *(const bf16x8*)&sW2[16 + lr][s2 * 32 + jb * 8];
#pragma unroll
            for (int m = 0; m < 2; m++) {
                bf16x8 a2 = *(const bf16x8*)&myC1[m * 16 + lr][s2 * 32 + jb * 8];
                acc2[m][0] = MFMA16(a2, w2f0, acc2[m][0]);
                acc2[m][1] = MFMA16(a2, w2f1, acc2[m][1]);
            }
        }

        // epilogue: fp32 msgs in CSR-slot order
#pragma unroll
        for (int m = 0; m < 2; m++) {
            size_t sb = slotBase + (size_t)(half * 2 + m) * 16 + jb * 4;
#pragma unroll
            for (int r4 = 0; r4 < 4; r4++) {
                float* dst = &msgs[(sb + r4) * 32];
                dst[lr] = acc2[m][0][r4];
                dst[16 + lr] = acc2[m][1][r4];
            }
        }
    }
}

// ---------------- edge history LSTM + bf16 padded full table ----------------
__global__ __launch_bounds__(256) void edge_lstm_k(
    const float* __restrict__ agg, const float* __restrict__ cnt,
    const float* __restrict__ h0, const float* __restrict__ c0,
    const float* __restrict__ Wih, const float* __restrict__ Whh,
    const float* __restrict__ bih, const float* __restrict__ bhh,
    const float* __restrict__ node_h,
    float* __restrict__ h_out, float* __restrict__ c_out, ushort_t* __restrict__ full16)
{
    __shared__ float sWih[32 * 32];
    __shared__ float sWhh[32 * 8];
    __shared__ float sb[32];
    for (int i = threadIdx.x; i < 32 * 32; i += 256) sWih[i] = Wih[i];
    for (int i = threadIdx.x; i < 32 * 8; i += 256) sWhh[i] = Whh[i];
    if (threadIdx.x < 32) sb[threadIdx.x] = bih[threadIdx.x] + bhh[threadIdx.x];
    __syncthreads();
    int n = blockIdx.x * 256 + threadIdx.x;
    if (n >= NN) return;

    float inv = 1.0f / fmaxf(cnt[n], 1.0f);
    float msg[32];
#pragma unroll
    for (int k = 0; k < 32; k++) msg[k] = agg[(size_t)n * 32 + k] * inv;
    float h[8];
#pragma unroll
    for (int k = 0; k < 8; k++) h[k] = h0[n * 8 + k];

    float fl[32];
#pragma unroll
    for (int k = 0; k < 20; k++) fl[k] = node_h[n * 20 + k];
    fl[28] = 0.f; fl[29] = 0.f; fl[30] = 0.f; fl[31] = 0.f;

#pragma unroll
    for (int r = 0; r < 8; r++) {
        float gi = sb[r], gf = sb[8 + r], gg = sb[16 + r], go = sb[24 + r];
#pragma unroll
        for (int k = 0; k < 32; k++) {
            float v = msg[k];
            gi = fmaf(v, sWih[r * 32 + k], gi);
            gf = fmaf(v, sWih[(8 + r) * 32 + k], gf);
            gg = fmaf(v, sWih[(16 + r) * 32 + k], gg);
            go = fmaf(v, sWih[(24 + r) * 32 + k], go);
        }
#pragma unroll
        for (int k = 0; k < 8; k++) {
            float v = h[k];
            gi = fmaf(v, sWhh[r * 8 + k], gi);
            gf = fmaf(v, sWhh[(8 + r) * 8 + k], gf);
            gg = fmaf(v, sWhh[(16 + r) * 8 + k], gg);
            go = fmaf(v, sWhh[(24 + r) * 8 + k], go);
        }
        float cr = c0[n * 8 + r];
        float cn = sigmoidf_(gf) * cr + sigmoidf_(gi) * tanhf(gg);
        float hn = sigmoidf_(go) * tanhf(cn);
        h_out[n * 8 + r] = hn;
        c_out[n * 8 + r] = cn;
        fl[20 + r] = hn;
    }
    // bf16 padded full row [32] as 4 x uint4
    unsigned w[16];
#pragma unroll
    for (int k = 0; k < 16; k++) w[k] = pk2(fl[2 * k], fl[2 * k + 1]);
    uint4* dst = (uint4*)(full16 + (size_t)n * 32);
#pragma unroll
    for (int q = 0; q < 4; q++)
        dst[q] = make_uint4(w[q * 4], w[q * 4 + 1], w[q * 4 + 2], w[q * 4 + 3]);
}

// ---------------- output node MLP (reads bf16 full) ----------------
__global__ __launch_bounds__(256) void node_out_k(
    const ushort_t* __restrict__ full16, const float* __restrict__ agg2, const float* __restrict__ cnt,
    const float* __restrict__ W1, const float* __restrict__ b1,
    const float* __restrict__ W2, const float* __restrict__ b2,
    float* __restrict__ out)
{
    __shared__ __align__(16) float sW1[60 * 64];
    __shared__ __align__(16) float sW2[64 * 4];
    __shared__ float sb1[64];
    __shared__ float sb2[4];
    for (int i = threadIdx.x; i < 60 * 64; i += 256) sW1[i] = W1[i];
    for (int i = threadIdx.x; i < 64 * 4; i += 256) sW2[i] = W2[i];
    if (threadIdx.x < 64) sb1[threadIdx.x] = b1[threadIdx.x];
    if (threadIdx.x < 4) sb2[threadIdx.x] = b2[threadIdx.x];
    __syncthreads();
    int n = blockIdx.x * 256 + threadIdx.x;
    if (n >= NN) return;

    float in[60];
    const ushort_t* fr = full16 + (size_t)n * 32;
#pragma unroll
    for (int k = 0; k < 28; k++) in[k] = bf2f(fr[k]);
    float inv = 1.0f / fmaxf(cnt[n], 1.0f);
#pragma unroll
    for (int k = 0; k < 32; k++) in[28 + k] = agg2[(size_t)n * 32 + k] * inv;

    float o[4] = {sb2[0], sb2[1], sb2[2], sb2[3]};
#pragma unroll 1
    for (int j = 0; j < 64; j += 4) {
        float s[4] = {sb1[j], sb1[j + 1], sb1[j + 2], sb1[j + 3]};
#pragma unroll
        for (int k = 0; k < 60; k++) {
            float4 w = *(const float4*)&sW1[k * 64 + j];
            s[0] = fmaf(in[k], w.x, s[0]);
            s[1] = fmaf(in[k], w.y, s[1]);
            s[2] = fmaf(in[k], w.z, s[2]);
            s[3] = fmaf(in[k], w.w, s[3]);
        }
#pragma unroll
        for (int jj = 0; jj < 4; jj++) {
            float sv = fmaxf(s[jj], 0.0f);
            float4 w = *(const float4*)&sW2[(j + jj) * 4];
            o[0] = fmaf(sv, w.x, o[0]);
            o[1] = fmaf(sv, w.y, o[1]);
            o[2] = fmaf(sv, w.z, o[2]);
            o[3] = fmaf(sv, w.w, o[3]);
        }
    }
#pragma unroll
    for (int m = 0; m < 4; m++) out[n * 4 + m] = o[m];
}

// ---------------- fallback atomic edge MLP (reads bf16 tables) ----------------
template <int F, int STRIDE, bool DO_CNT>
__global__ __launch_bounds__(256) void edge_mlp_atomic_k(
    const ushort_t* __restrict__ feat,
    const int* __restrict__ row, const int* __restrict__ col,
    const float* __restrict__ eattr,
    const float* __restrict__ W1, const float* __restrict__ b1,
    const float* __restrict__ W2, const float* __restrict__ b2,
    float* __restrict__ agg, float* __restrict__ cnt)
{
    constexpr int IN = 2 * F + 4;
    __shared__ __align__(16) float sW1[IN * 64];
    __shared__ __align__(16) float sW2[64 * 32];
    __shared__ float sb1[64];
    __shared__ float sb2[32];
    for (int i = threadIdx.x; i < IN * 64; i += 256) sW1[i] = W1[i];
    for (int i = threadIdx.x; i < 64 * 32; i += 256) sW2[i] = W2[i];
    if (threadIdx.x < 64) sb1[threadIdx.x] = b1[threadIdx.x];
    if (threadIdx.x < 32) sb2[threadIdx.x] = b2[threadIdx.x];
    __syncthreads();
    int e = blockIdx.x * 256 + threadIdx.x;
    if (e >= EE) return;

    int r = row[e], c = col[e];
    float h[IN];
#pragma unroll
    for (int k = 0; k < F; k++) h[k] = bf2f(feat[(size_t)r * STRIDE + k]);
#pragma unroll
    for (int k = 0; k < F; k++) h[F + k] = bf2f(feat[(size_t)c * STRIDE + k]);
    float4 ev = *(const float4*)&eattr[(size_t)e * 4];
    h[2 * F] = ev.x; h[2 * F + 1] = ev.y; h[2 * F + 2] = ev.z; h[2 * F + 3] = ev.w;

    float out[32];
#pragma unroll
    for (int m = 0; m < 32; m++) out[m] = sb2[m];
#pragma unroll 1
    for (int j = 0; j < 64; j += 4) {
        float s[4] = {sb1[j], sb1[j + 1], sb1[j + 2], sb1[j + 3]};
#pragma unroll
        for (int k = 0; k < IN; k++) {
            float4 w = *(const float4*)&sW1[k * 64 + j];
            s[0] = fmaf(h[k], w.x, s[0]);
            s[1] = fmaf(h[k], w.y, s[1]);
            s[2] = fmaf(h[k], w.z, s[2]);
            s[3] = fmaf(h[k], w.w, s[3]);
        }
        s[0] = fmaxf(s[0], 0.f); s[1] = fmaxf(s[1], 0.f);
        s[2] = fmaxf(s[2], 0.f); s[3] = fmaxf(s[3], 0.f);
#pragma unroll
        for (int jj = 0; jj < 4; jj++) {
#pragma unroll
            for (int m = 0; m < 32; m += 4) {
                float4 w = *(const float4*)&sW2[(j + jj) * 32 + m];
                out[m]     = fmaf(s[jj], w.x, out[m]);
                out[m + 1] = fmaf(s[jj], w.y, out[m + 1]);
                out[m + 2] = fmaf(s[jj], w.z, out[m + 2]);
                out[m + 3] = fmaf(s[jj], w.w, out[m + 3]);
            }
        }
    }
    float* dst = &agg[(size_t)c * 32];
#pragma unroll
    for (int m = 0; m < 32; m++) atomicAdd(&dst[m], out[m]);
    if (DO_CNT) atomicAdd(&cnt[c], 1.0f);
}

extern "C" void kernel_launch(void* const* d_in, const int* in_sizes, int n_in,
                              void* d_out, int out_size, void* d_ws, size_t ws_size,
                              hipStream_t stream) {
    (void)in_sizes; (void)n_in; (void)out_size;
    const float* x      = (const float*)d_in[0];
    const float* u      = (const float*)d_in[1];
    const int*   ei     = (const int*)d_in[2];
    const float* eattr  = (const float*)d_in[3];
    const float* hn_h   = (const float*)d_in[4];
    const float* hn_c   = (const float*)d_in[5];
    const float* he_h   = (const float*)d_in[6];
    const float* he_c   = (const float*)d_in[7];
    const float* Wih_n  = (const float*)d_in[8];
    const float* Whh_n  = (const float*)d_in[9];
    const float* bih_n  = (const float*)d_in[10];
    const float* bhh_n  = (const float*)d_in[11];
    const float* Wih_e  = (const float*)d_in[12];
    const float* Whh_e  = (const float*)d_in[13];
    const float* bih_e  = (const float*)d_in[14];
    const float* bhh_e  = (const float*)d_in[15];
    const float* We1    = (const float*)d_in[16];
    const float* be1    = (const float*)d_in[17];
    const float* We2    = (const float*)d_in[18];
    const float* be2    = (const float*)d_in[19];
    const float* Wo1    = (const float*)d_in[20];
    const float* bo1    = (const float*)d_in[21];
    const float* Wo2    = (const float*)d_in[22];
    const float* bo2    = (const float*)d_in[23];
    const float* Wn1    = (const float*)d_in[24];
    const float* bn1    = (const float*)d_in[25];
    const float* Wn2    = (const float*)d_in[26];
    const float* bn2    = (const float*)d_in[27];

    const int* row = ei;
    const int* col = ei + EE;

    float* out = (float*)d_out;
    float* out_y   = out;                        // [N,4]
    float* node_h  = out + (size_t)NN * 4;       // [N,20]
    float* node_c  = out + (size_t)NN * 24;      // [N,20]
    float* edge_h  = out + (size_t)NN * 44;      // [N,8]
    float* edge_c  = out + (size_t)NN * 52;      // [N,8]

    int nb_n = (NN + 255) / 256;
    int nb_e = (EE + 255) / 256;

    // ---- workspace layout (byte-offset based) ----
    // xu16 bf16[N][40] | full16 bf16[N][32] | agg f32[N*32] | cntf[N] | agg2[N*32] |
    // count,cursor,offset int[N] | bsum,bpre int[SBLK] | rowp,colp int[E] |
    // eap bf16[(E+4)*4] | msgs f32[E*32]
    ushort_t* xu16   = (ushort_t*)d_ws;
    ushort_t* full16 = xu16 + (size_t)NN * 40;
    float* agg  = (float*)(full16 + (size_t)NN * 32);
    float* cntf = agg + (size_t)NN * 32;
    float* agg2 = cntf + NN;
    int* count  = (int*)(agg2 + (size_t)NN * 32);
    int* cursor = count + NN;
    int* offset = cursor + NN;
    int* bsum   = offset + NN;
    int* bpre   = bsum + SBLK;
    int* rowp   = bpre + SBLK;
    int* colp   = rowp + EE;
    ushort_t* eap = (ushort_t*)(colp + EE);
    float* msgs = (float*)(eap + (size_t)(EE + 4) * 4);
    size_t needed = (size_t)((char*)(msgs + (size_t)EE * 32) - (char*)d_ws);

    if (ws_size >= needed) {
        hipMemsetAsync(count, 0, 2 * (size_t)NN * sizeof(int), stream);  // count + cursor

        node_lstm_k<<<nb_n, 256, 0, stream>>>(x, u, hn_h, hn_c, Wih_n, Whh_n, bih_n, bhh_n,
                                              xu16, node_h, node_c);
        csr_count_k<<<nb_e, 256, 0, stream>>>(col, count);
        scan1_k<<<SBLK, 256, 0, stream>>>(count, bsum);
        scan2_k<<<1, 256, 0, stream>>>(bsum, bpre);
        scan3_k<<<SBLK, 256, 0, stream>>>(count, bpre, offset, cntf);
        csr_fill3_k<<<nb_e, 256, 0, stream>>>(row, col, eattr, offset, cursor, rowp, colp, eap);

        edge_mlp_mfma2_k<37, 40, 96><<<EE / 256, 256, 0, stream>>>(
            xu16, rowp, colp, eap, We1, be1, We2, be2, msgs);
        seg_sum2_k<<<(NN + 7) / 8, 256, 0, stream>>>(msgs, offset, count, agg);
        edge_lstm_k<<<nb_n, 256, 0, stream>>>(agg, cntf, he_h, he_c, Wih_e, Whh_e, bih_e, bhh_e,
                                              node_h, edge_h, edge_c, full16);
        edge_mlp_mfma2_k<28, 32, 64><<<EE / 256, 256, 0, stream>>>(
            full16, rowp, colp, eap, Wo1, bo1, Wo2, bo2, msgs);
        seg_sum2_k<<<(NN + 7) / 8, 256, 0, stream>>>(msgs, offset, count, agg2);
        node_out_k<<<nb_n, 256, 0, stream>>>(full16, agg2, cntf, Wn1, bn1, Wn2, bn2, out_y);
    } else {
        // fallback: atomic scatter path
        hipMemsetAsync(agg, 0, (size_t)NN * (32 + 1 + 32) * sizeof(float), stream);
        node_lstm_k<<<nb_n, 256, 0, stream>>>(x, u, hn_h, hn_c, Wih_n, Whh_n, bih_n, bhh_n,
                                              xu16, node_h, node_c);
        edge_mlp_atomic_k<37, 40, true><<<nb_e, 256, 0, stream>>>(xu16, row, col, eattr,
                                                                  We1, be1, We2, be2, agg, cntf);
        edge_lstm_k<<<nb_n, 256, 0, stream>>>(agg, cntf, he_h, he_c, Wih_e, Whh_e, bih_e, bhh_e,
                                              node_h, edge_h, edge_c, full16);
        edge_mlp_atomic_k<28, 32, false><<<nb_e, 256, 0, stream>>>(full16, row, col, eattr,
                                                                   Wo1, bo1, Wo2, bo2, agg2, nullptr);
        node_out_k<<<nb_n, 256, 0, stream>>>(full16, agg2, cntf, Wn1, bn1, Wn2, bn2, out_y);
    }
}

// Round 6
// 289.449 us; speedup vs baseline: 10.4055x; 1.2073x over previous
//
#include <hip/hip_runtime.h>
#include <math.h>

#define NN 50000
#define EE 800000
#define SBLK ((NN + 255) / 256)   // 196 scan blocks

typedef short bf16x8 __attribute__((ext_vector_type(8)));
typedef float f32x4 __attribute__((ext_vector_type(4)));
typedef unsigned short ushort_t;
#define MFMA16(a, b, c) __builtin_amdgcn_mfma_f32_16x16x32_bf16(a, b, c, 0, 0, 0)

__device__ __forceinline__ float sigmoidf_(float x) { return 1.0f / (1.0f + __expf(-x)); }

__device__ __forceinline__ unsigned short f2bf(float f) {
    unsigned u = __builtin_bit_cast(unsigned, f);
    u += 0x7FFFu + ((u >> 16) & 1u);
    return (unsigned short)(u >> 16);
}
__device__ __forceinline__ float bf2f(unsigned short v) {
    unsigned u = (unsigned)v << 16;
    return __builtin_bit_cast(float, u);
}
__device__ __forceinline__ unsigned pk2(float a, float b) {
    return ((unsigned)f2bf(b) << 16) | (unsigned)f2bf(a);
}

// ---------------- node history LSTM + bf16 padded xu table ----------------
__global__ __launch_bounds__(256) void node_lstm_k(
    const float* __restrict__ x, const float* __restrict__ u,
    const float* __restrict__ h0, const float* __restrict__ c0,
    const float* __restrict__ Wih, const float* __restrict__ Whh,
    const float* __restrict__ bih, const float* __restrict__ bhh,
    ushort_t* __restrict__ xu16, float* __restrict__ h_out, float* __restrict__ c_out)
{
    __shared__ float sWih[80 * 37];
    __shared__ float sWhh[80 * 20];
    __shared__ float sb[80];
    for (int i = threadIdx.x; i < 80 * 37; i += 256) sWih[i] = Wih[i];
    for (int i = threadIdx.x; i < 80 * 20; i += 256) sWhh[i] = Whh[i];
    if (threadIdx.x < 80) sb[threadIdx.x] = bih[threadIdx.x] + bhh[threadIdx.x];
    __syncthreads();
    int n = blockIdx.x * 256 + threadIdx.x;
    if (n >= NN) return;

    float xu[40];
#pragma unroll
    for (int k = 0; k < 5; k++) xu[k] = x[n * 5 + k];
#pragma unroll
    for (int k = 0; k < 32; k++) xu[5 + k] = u[n * 32 + k];
    xu[37] = 0.f; xu[38] = 0.f; xu[39] = 0.f;

    {
        unsigned w[20];
#pragma unroll
        for (int k = 0; k < 20; k++) w[k] = pk2(xu[2 * k], xu[2 * k + 1]);
        uint4* dst = (uint4*)(xu16 + (size_t)n * 40);
#pragma unroll
        for (int q = 0; q < 5; q++)
            dst[q] = make_uint4(w[q * 4], w[q * 4 + 1], w[q * 4 + 2], w[q * 4 + 3]);
    }

    float h[20];
#pragma unroll
    for (int k = 0; k < 20; k++) h[k] = h0[n * 20 + k];

#pragma unroll 1
    for (int r = 0; r < 20; r++) {
        float gi = sb[r], gf = sb[20 + r], gg = sb[40 + r], go = sb[60 + r];
#pragma unroll
        for (int k = 0; k < 37; k++) {
            float v = xu[k];
            gi = fmaf(v, sWih[r * 37 + k], gi);
            gf = fmaf(v, sWih[(20 + r) * 37 + k], gf);
            gg = fmaf(v, sWih[(40 + r) * 37 + k], gg);
            go = fmaf(v, sWih[(60 + r) * 37 + k], go);
        }
#pragma unroll
        for (int k = 0; k < 20; k++) {
            float v = h[k];
            gi = fmaf(v, sWhh[r * 20 + k], gi);
            gf = fmaf(v, sWhh[(20 + r) * 20 + k], gf);
            gg = fmaf(v, sWhh[(40 + r) * 20 + k], gg);
            go = fmaf(v, sWhh[(60 + r) * 20 + k], go);
        }
        float cr = c0[n * 20 + r];
        float cn = sigmoidf_(gf) * cr + sigmoidf_(gi) * tanhf(gg);
        float hn = sigmoidf_(go) * tanhf(cn);
        h_out[n * 20 + r] = hn;
        c_out[n * 20 + r] = cn;
    }
}

// ---------------- CSR build ----------------
__global__ __launch_bounds__(256) void csr_count_k(const int* __restrict__ col,
                                                   int* __restrict__ count)
{
    int e = blockIdx.x * 256 + threadIdx.x;
    if (e < EE) atomicAdd(&count[col[e]], 1);
}

__global__ __launch_bounds__(256) void scan1_k(const int* __restrict__ count,
                                               int* __restrict__ bsum)
{
    __shared__ int red[256];
    int t = threadIdx.x;
    int i = blockIdx.x * 256 + t;
    red[t] = (i < NN) ? count[i] : 0;
    __syncthreads();
#pragma unroll
    for (int d = 128; d > 0; d >>= 1) {
        if (t < d) red[t] += red[t + d];
        __syncthreads();
    }
    if (t == 0) bsum[blockIdx.x] = red[0];
}

__global__ __launch_bounds__(256) void scan2_k(const int* __restrict__ bsum,
                                               int* __restrict__ bpre)
{
    __shared__ int s[256];
    int t = threadIdx.x;
    int v = (t < SBLK) ? bsum[t] : 0;
    s[t] = v;
    __syncthreads();
#pragma unroll
    for (int d = 1; d < 256; d <<= 1) {
        int w = (t >= d) ? s[t - d] : 0;
        __syncthreads();
        s[t] += w;
        __syncthreads();
    }
    if (t < SBLK) bpre[t] = s[t] - v;
}

__global__ __launch_bounds__(256) void scan3_k(const int* __restrict__ count,
                                               const int* __restrict__ bpre,
                                               int* __restrict__ offset,
                                               float* __restrict__ cntf)
{
    __shared__ int s[256];
    int t = threadIdx.x;
    int i = blockIdx.x * 256 + t;
    int v = (i < NN) ? count[i] : 0;
    s[t] = v;
    __syncthreads();
#pragma unroll
    for (int d = 1; d < 256; d <<= 1) {
        int w = (t >= d) ? s[t - d] : 0;
        __syncthreads();
        s[t] += w;
        __syncthreads();
    }
    if (i < NN) {
        offset[i] = bpre[blockIdx.x] + s[t] - v;
        cntf[i] = (float)v;
    }
}

// fill CSR: slot-ordered row/col + slot-ordered bf16 eattr
__global__ __launch_bounds__(256) void csr_fill3_k(const int* __restrict__ row,
                                                   const int* __restrict__ col,
                                                   const float* __restrict__ eattr,
                                                   const int* __restrict__ offset,
                                                   int* __restrict__ cursor,
                                                   int* __restrict__ rowp,
                                                   int* __restrict__ colp,
                                                   ushort_t* __restrict__ eap)
{
    int e = blockIdx.x * 256 + threadIdx.x;
    if (e >= EE) return;
    int c = col[e];
    int pos = atomicAdd(&cursor[c], 1);
    int slot = offset[c] + pos;
    rowp[slot] = row[e];
    colp[slot] = c;
    float4 ev = *(const float4*)&eattr[(size_t)e * 4];
    uint2 pk = make_uint2(pk2(ev.x, ev.y), pk2(ev.z, ev.w));
    *(uint2*)&eap[(size_t)slot * 4] = pk;
}

// ---------------- fused 2-layer edge MLP + in-block segment sum ----------------
// Per block: 256 CSR-contiguous edges. MFMA MLP as round 5, but layer-2 outputs
// stay in VGPRs; then the block's [256 edges][32 feats] tile goes to LDS
// (aliased over the weight/C1 region) and is reduced per node in-block:
// complete segments -> plain store to agg; boundary segments -> atomicAdd.
template <int F, int STRIDE, int INK>
__global__ __launch_bounds__(256, 4) void edge_mlp_fused_k(
    const ushort_t* __restrict__ feat,
    const int* __restrict__ rowp, const int* __restrict__ colp,
    const ushort_t* __restrict__ eap,
    const int* __restrict__ offset, const int* __restrict__ count,
    const float* __restrict__ W1, const float* __restrict__ b1,
    const float* __restrict__ W2, const float* __restrict__ b2,
    float* __restrict__ agg)
{
    constexpr int S1 = INK / 32;
    constexpr int W1ST = INK + 8;
    constexpr int C1ST = 72;
    constexpr int ABYTES = (64 * W1ST + 32 * C1ST + 4 * 32 * C1ST) * 2;
    constexpr int BBYTES = 32 * 257 * 4;            // msg tile [32 feat][257] f32
    constexpr int UBYTES = (ABYTES > BBYTES) ? ABYTES : BBYTES;

    __shared__ __align__(16) char ldsu[UBYTES];
    __shared__ int colLds[256];
    __shared__ unsigned char segStartA[256];
    __shared__ short segEndA[256];                  // negative => complete segment
    __shared__ int segCnt;

    ushort_t* sW1 = (ushort_t*)ldsu;                // [64][W1ST]
    ushort_t* sW2 = sW1 + 64 * W1ST;                // [32][C1ST]
    ushort_t* sC1 = sW2 + 32 * C1ST;                // [4][32][C1ST]
    float*    msgT = (float*)ldsu;                  // [32][257]

    const int tid = threadIdx.x;
    const int B0 = blockIdx.x * 256;
    if (tid == 0) segCnt = 0;
    colLds[tid] = colp[B0 + tid];

    // stage W1 with K-remap to the gather layout (pad rows zeroed)
    for (int i = tid; i < 64 * INK; i += 256) {
        int nk = i >> 6, n = i & 63;
        int kp = 0; bool z = false;
        if (F == 37) {
            if (nk < 37) kp = nk;
            else if (nk < 40) z = true;
            else if (nk < 77) kp = nk - 3;
            else if (nk < 80) z = true;
            else if (nk < 84) kp = nk - 6;
            else z = true;
        } else {
            if (nk < 28) kp = nk;
            else if (nk < 32) z = true;
            else kp = nk - 4;
        }
        sW1[n * W1ST + nk] = z ? (ushort_t)0 : f2bf(W1[kp * 64 + n]);
    }
    for (int i = tid; i < 64 * 32; i += 256) {
        int k = i >> 5, n = i & 31;
        sW2[n * C1ST + k] = f2bf(W2[k * 32 + n]);
    }
    __syncthreads();

    // build segment list (colp is sorted within the block)
    {
        bool isStart = (tid == 0) || (colLds[tid] != colLds[tid - 1]);
        if (isStart) {
            int node = colLds[tid];
            int off = offset[node], cn = count[node];
            int e = off + cn - B0; if (e > 256) e = 256;
            bool fullseg = (off >= B0) && (off + cn <= B0 + 256);
            int j = atomicAdd(&segCnt, 1);
            segStartA[j] = (unsigned char)tid;
            segEndA[j] = (short)(fullseg ? -e : e);
        }
    }

    const int wave = tid >> 6, lane = tid & 63;
    const int lr = lane & 15, jb = lane >> 4;
    const size_t slotBase = (size_t)B0 + (size_t)wave * 64;
    const float4* b1v = (const float4*)b1;
    ushort_t* myC1 = sC1 + wave * 32 * C1ST;        // [32][C1ST]
    const float bb2_0 = b2[lr], bb2_1 = b2[16 + lr];

    f32x4 acc2a[2][2][2];                           // [half][m][n]

#pragma unroll
    for (int half = 0; half < 2; half++) {
        // gather B-fragments (2 ne-tiles x S1 chunks), each one aligned 16B load
        bf16x8 xf[2][S1];
#pragma unroll
        for (int ne2 = 0; ne2 < 2; ne2++) {
            size_t slot = slotBase + (size_t)(half * 2 + ne2) * 16 + lr;
            const ushort_t* xr = feat + (size_t)rowp[slot] * STRIDE;
            const ushort_t* xc = feat + (size_t)colLds[slot - B0] * STRIDE;
            const ushort_t* ea = eap + slot * 4;
            xf[ne2][0] = *(const bf16x8*)(xr + jb * 8);
            if (F == 37) {
                const ushort_t* p1 = (jb == 0) ? (xr + 32) : (xc + (jb - 1) * 8);
                xf[ne2][1] = *(const bf16x8*)p1;
                const ushort_t* p2 = (jb == 0) ? (xc + 24) : ((jb == 1) ? (xc + 32) : ea);
                bf16x8 v = *(const bf16x8*)p2;
                if (jb >= 2) { v[4] = 0; v[5] = 0; v[6] = 0; v[7] = 0; }
                if (jb == 3) { v[0] = 0; v[1] = 0; v[2] = 0; v[3] = 0; }
                xf[ne2][2] = v;
            } else {
                const ushort_t* pl = (jb < 3) ? (xc + jb * 8) : (xc + 24);
                uint2 lo = *(const uint2*)pl;
                const ushort_t* ph = (jb < 3) ? (pl + 4) : ea;
                uint2 hi = *(const uint2*)ph;
                uint4 cc = make_uint4(lo.x, lo.y, hi.x, hi.y);
                xf[ne2][1] = __builtin_bit_cast(bf16x8, cc);
            }
        }

        // layer 1: D1[hid][edge], bias in C-init
        f32x4 acc1[4][2];
#pragma unroll
        for (int mh = 0; mh < 4; mh++) {
            float4 bv = b1v[mh * 4 + jb];
            f32x4 bi = {bv.x, bv.y, bv.z, bv.w};
            acc1[mh][0] = bi; acc1[mh][1] = bi;
        }
#pragma unroll
        for (int s = 0; s < S1; s++) {
#pragma unroll
            for (int mh = 0; mh < 4; mh++) {
                bf16x8 wf = *(const bf16x8*)&sW1[(mh * 16 + lr) * W1ST + s * 32 + jb * 8];
                acc1[mh][0] = MFMA16(wf, xf[0][s], acc1[mh][0]);
                acc1[mh][1] = MFMA16(wf, xf[1][s], acc1[mh][1]);
            }
        }

        // relu -> bf16 -> packed b64 stores into wave-private C1 [edge32][hid]
#pragma unroll
        for (int mh = 0; mh < 4; mh++) {
#pragma unroll
            for (int ne2 = 0; ne2 < 2; ne2++) {
                f32x4 a = acc1[mh][ne2];
                unsigned w0 = pk2(fmaxf(a[0], 0.f), fmaxf(a[1], 0.f));
                unsigned w1 = pk2(fmaxf(a[2], 0.f), fmaxf(a[3], 0.f));
                *(uint2*)&myC1[(ne2 * 16 + lr) * C1ST + mh * 16 + jb * 4] = make_uint2(w0, w1);
            }
        }

        // layer 2: D2[edge][hid2], bias in C-init
#pragma unroll
        for (int m = 0; m < 2; m++) {
            acc2a[half][m][0] = f32x4{bb2_0, bb2_0, bb2_0, bb2_0};
            acc2a[half][m][1] = f32x4{bb2_1, bb2_1, bb2_1, bb2_1};
        }
#pragma unroll
        for (int s2 = 0; s2 < 2; s2++) {
            bf16x8 w2f0 = *(const bf16x8*)&sW2[lr * C1ST + s2 * 32 + jb * 8];
            bf16x8 w2f1 = *(const bf16x8*)&sW2[(16 + lr) * C1ST + s2 * 32 + jb * 8];
#pragma unroll
            for (int m = 0; m < 2; m++) {
                bf16x8 a2 = *(const bf16x8*)&myC1[(m * 16 + lr) * C1ST + s2 * 32 + jb * 8];
                acc2a[half][m][0] = MFMA16(a2, w2f0, acc2a[half][m][0]);
                acc2a[half][m][1] = MFMA16(a2, w2f1, acc2a[half][m][1]);
            }
        }
    }

    // all waves done with sW1/sW2/sC1 -> alias the region as the msg tile
    __syncthreads();
#pragma unroll
    for (int half = 0; half < 2; half++) {
#pragma unroll
        for (int m = 0; m < 2; m++) {
            int row = wave * 64 + (half * 2 + m) * 16 + jb * 4;   // + r4
#pragma unroll
            for (int n = 0; n < 2; n++) {
                f32x4 a = acc2a[half][m][n];
                float* dst = &msgT[(size_t)(n * 16 + lr) * 257 + row];
                dst[0] = a[0]; dst[1] = a[1]; dst[2] = a[2]; dst[3] = a[3];
            }
        }
    }
    __syncthreads();

    // per-node reduction: wave w handles segments w, w+4, ...
    {
        int f = lane & 31;
        int h = lane >> 5;
        const float* mrow = msgT + (size_t)f * 257;
        int nseg = segCnt;
        for (int j = wave; j < nseg; j += 4) {
            int s = segStartA[j];
            int ev = segEndA[j];
            bool fullseg = ev < 0;
            int e = fullseg ? -ev : ev;
            int node = colLds[s];
            float sum = 0.f;
            for (int i = s + h; i < e; i += 2) sum += mrow[i];
            sum += __shfl_xor(sum, 32);
            if (lane < 32) {
                float* dst = &agg[(size_t)node * 32 + f];
                if (fullseg) *dst = sum;
                else atomicAdd(dst, sum);
            }
        }
    }
}

// ---------------- edge history LSTM + bf16 padded full table ----------------
__global__ __launch_bounds__(256) void edge_lstm_k(
    const float* __restrict__ agg, const float* __restrict__ cnt,
    const float* __restrict__ h0, const float* __restrict__ c0,
    const float* __restrict__ Wih, const float* __restrict__ Whh,
    const float* __restrict__ bih, const float* __restrict__ bhh,
    const float* __restrict__ node_h,
    float* __restrict__ h_out, float* __restrict__ c_out, ushort_t* __restrict__ full16)
{
    __shared__ float sWih[32 * 32];
    __shared__ float sWhh[32 * 8];
    __shared__ float sb[32];
    for (int i = threadIdx.x; i < 32 * 32; i += 256) sWih[i] = Wih[i];
    for (int i = threadIdx.x; i < 32 * 8; i += 256) sWhh[i] = Whh[i];
    if (threadIdx.x < 32) sb[threadIdx.x] = bih[threadIdx.x] + bhh[threadIdx.x];
    __syncthreads();
    int n = blockIdx.x * 256 + threadIdx.x;
    if (n >= NN) return;

    float inv = 1.0f / fmaxf(cnt[n], 1.0f);
    float msg[32];
#pragma unroll
    for (int k = 0; k < 32; k++) msg[k] = agg[(size_t)n * 32 + k] * inv;
    float h[8];
#pragma unroll
    for (int k = 0; k < 8; k++) h[k] = h0[n * 8 + k];

    float fl[32];
#pragma unroll
    for (int k = 0; k < 20; k++) fl[k] = node_h[n * 20 + k];
    fl[28] = 0.f; fl[29] = 0.f; fl[30] = 0.f; fl[31] = 0.f;

#pragma unroll
    for (int r = 0; r < 8; r++) {
        float gi = sb[r], gf = sb[8 + r], gg = sb[16 + r], go = sb[24 + r];
#pragma unroll
        for (int k = 0; k < 32; k++) {
            float v = msg[k];
            gi = fmaf(v, sWih[r * 32 + k], gi);
            gf = fmaf(v, sWih[(8 + r) * 32 + k], gf);
            gg = fmaf(v, sWih[(16 + r) * 32 + k], gg);
            go = fmaf(v, sWih[(24 + r) * 32 + k], go);
        }
#pragma unroll
        for (int k = 0; k < 8; k++) {
            float v = h[k];
            gi = fmaf(v, sWhh[r * 8 + k], gi);
            gf = fmaf(v, sWhh[(8 + r) * 8 + k], gf);
            gg = fmaf(v, sWhh[(16 + r) * 8 + k], gg);
            go = fmaf(v, sWhh[(24 + r) * 8 + k], go);
        }
        float cr = c0[n * 8 + r];
        float cn = sigmoidf_(gf) * cr + sigmoidf_(gi) * tanhf(gg);
        float hn = sigmoidf_(go) * tanhf(cn);
        h_out[n * 8 + r] = hn;
        c_out[n * 8 + r] = cn;
        fl[20 + r] = hn;
    }
    unsigned w[16];
#pragma unroll
    for (int k = 0; k < 16; k++) w[k] = pk2(fl[2 * k], fl[2 * k + 1]);
    uint4* dst = (uint4*)(full16 + (size_t)n * 32);
#pragma unroll
    for (int q = 0; q < 4; q++)
        dst[q] = make_uint4(w[q * 4], w[q * 4 + 1], w[q * 4 + 2], w[q * 4 + 3]);
}

// ---------------- output node MLP (reads bf16 full) ----------------
__global__ __launch_bounds__(256) void node_out_k(
    const ushort_t* __restrict__ full16, const float* __restrict__ agg2, const float* __restrict__ cnt,
    const float* __restrict__ W1, const float* __restrict__ b1,
    const float* __restrict__ W2, const float* __restrict__ b2,
    float* __restrict__ out)
{
    __shared__ __align__(16) float sW1[60 * 64];
    __shared__ __align__(16) float sW2[64 * 4];
    __shared__ float sb1[64];
    __shared__ float sb2[4];
    for (int i = threadIdx.x; i < 60 * 64; i += 256) sW1[i] = W1[i];
    for (int i = threadIdx.x; i < 64 * 4; i += 256) sW2[i] = W2[i];
    if (threadIdx.x < 64) sb1[threadIdx.x] = b1[threadIdx.x];
    if (threadIdx.x < 4) sb2[threadIdx.x] = b2[threadIdx.x];
    __syncthreads();
    int n = blockIdx.x * 256 + threadIdx.x;
    if (n >= NN) return;

    float in[60];
    const ushort_t* fr = full16 + (size_t)n * 32;
#pragma unroll
    for (int k = 0; k < 28; k++) in[k] = bf2f(fr[k]);
    float inv = 1.0f / fmaxf(cnt[n], 1.0f);
#pragma unroll
    for (int k = 0; k < 32; k++) in[28 + k] = agg2[(size_t)n * 32 + k] * inv;

    float o[4] = {sb2[0], sb2[1], sb2[2], sb2[3]};
#pragma unroll 1
    for (int j = 0; j < 64; j += 4) {
        float s[4] = {sb1[j], sb1[j + 1], sb1[j + 2], sb1[j + 3]};
#pragma unroll
        for (int k = 0; k < 60; k++) {
            float4 w = *(const float4*)&sW1[k * 64 + j];
            s[0] = fmaf(in[k], w.x, s[0]);
            s[1] = fmaf(in[k], w.y, s[1]);
            s[2] = fmaf(in[k], w.z, s[2]);
            s[3] = fmaf(in[k], w.w, s[3]);
        }
#pragma unroll
        for (int jj = 0; jj < 4; jj++) {
            float sv = fmaxf(s[jj], 0.0f);
            float4 w = *(const float4*)&sW2[(j + jj) * 4];
            o[0] = fmaf(sv, w.x, o[0]);
            o[1] = fmaf(sv, w.y, o[1]);
            o[2] = fmaf(sv, w.z, o[2]);
            o[3] = fmaf(sv, w.w, o[3]);
        }
    }
#pragma unroll
    for (int m = 0; m < 4; m++) out[n * 4 + m] = o[m];
}

// ---------------- fallback atomic edge MLP (reads bf16 tables) ----------------
template <int F, int STRIDE, bool DO_CNT>
__global__ __launch_bounds__(256) void edge_mlp_atomic_k(
    const ushort_t* __restrict__ feat,
    const int* __restrict__ row, const int* __restrict__ col,
    const float* __restrict__ eattr,
    const float* __restrict__ W1, const float* __restrict__ b1,
    const float* __restrict__ W2, const float* __restrict__ b2,
    float* __restrict__ agg, float* __restrict__ cnt)
{
    constexpr int IN = 2 * F + 4;
    __shared__ __align__(16) float sW1[IN * 64];
    __shared__ __align__(16) float sW2[64 * 32];
    __shared__ float sb1[64];
    __shared__ float sb2[32];
    for (int i = threadIdx.x; i < IN * 64; i += 256) sW1[i] = W1[i];
    for (int i = threadIdx.x; i < 64 * 32; i += 256) sW2[i] = W2[i];
    if (threadIdx.x < 64) sb1[threadIdx.x] = b1[threadIdx.x];
    if (threadIdx.x < 32) sb2[threadIdx.x] = b2[threadIdx.x];
    __syncthreads();
    int e = blockIdx.x * 256 + threadIdx.x;
    if (e >= EE) return;

    int r = row[e], c = col[e];
    float h[IN];
#pragma unroll
    for (int k = 0; k < F; k++) h[k] = bf2f(feat[(size_t)r * STRIDE + k]);
#pragma unroll
    for (int k = 0; k < F; k++) h[F + k] = bf2f(feat[(size_t)c * STRIDE + k]);
    float4 ev = *(const float4*)&eattr[(size_t)e * 4];
    h[2 * F] = ev.x; h[2 * F + 1] = ev.y; h[2 * F + 2] = ev.z; h[2 * F + 3] = ev.w;

    float out[32];
#pragma unroll
    for (int m = 0; m < 32; m++) out[m] = sb2[m];
#pragma unroll 1
    for (int j = 0; j < 64; j += 4) {
        float s[4] = {sb1[j], sb1[j + 1], sb1[j + 2], sb1[j + 3]};
#pragma unroll
        for (int k = 0; k < IN; k++) {
            float4 w = *(const float4*)&sW1[k * 64 + j];
            s[0] = fmaf(h[k], w.x, s[0]);
            s[1] = fmaf(h[k], w.y, s[1]);
            s[2] = fmaf(h[k], w.z, s[2]);
            s[3] = fmaf(h[k], w.w, s[3]);
        }
        s[0] = fmaxf(s[0], 0.f); s[1] = fmaxf(s[1], 0.f);
        s[2] = fmaxf(s[2], 0.f); s[3] = fmaxf(s[3], 0.f);
#pragma unroll
        for (int jj = 0; jj < 4; jj++) {
#pragma unroll
            for (int m = 0; m < 32; m += 4) {
                float4 w = *(const float4*)&sW2[(j + jj) * 32 + m];
                out[m]     = fmaf(s[jj], w.x, out[m]);
                out[m + 1] = fmaf(s[jj], w.y, out[m + 1]);
                out[m + 2] = fmaf(s[jj], w.z, out[m + 2]);
                out[m + 3] = fmaf(s[jj], w.w, out[m + 3]);
            }
        }
    }
    float* dst = &agg[(size_t)c * 32];
#pragma unroll
    for (int m = 0; m < 32; m++) atomicAdd(&dst[m], out[m]);
    if (DO_CNT) atomicAdd(&cnt[c], 1.0f);
}

extern "C" void kernel_launch(void* const* d_in, const int* in_sizes, int n_in,
                              void* d_out, int out_size, void* d_ws, size_t ws_size,
                              hipStream_t stream) {
    (void)in_sizes; (void)n_in; (void)out_size;
    const float* x      = (const float*)d_in[0];
    const float* u      = (const float*)d_in[1];
    const int*   ei     = (const int*)d_in[2];
    const float* eattr  = (const float*)d_in[3];
    const float* hn_h   = (const float*)d_in[4];
    const float* hn_c   = (const float*)d_in[5];
    const float* he_h   = (const float*)d_in[6];
    const float* he_c   = (const float*)d_in[7];
    const float* Wih_n  = (const float*)d_in[8];
    const float* Whh_n  = (const float*)d_in[9];
    const float* bih_n  = (const float*)d_in[10];
    const float* bhh_n  = (const float*)d_in[11];
    const float* Wih_e  = (const float*)d_in[12];
    const float* Whh_e  = (const float*)d_in[13];
    const float* bih_e  = (const float*)d_in[14];
    const float* bhh_e  = (const float*)d_in[15];
    const float* We1    = (const float*)d_in[16];
    const float* be1    = (const float*)d_in[17];
    const float* We2    = (const float*)d_in[18];
    const float* be2    = (const float*)d_in[19];
    const float* Wo1    = (const float*)d_in[20];
    const float* bo1    = (const float*)d_in[21];
    const float* Wo2    = (const float*)d_in[22];
    const float* bo2    = (const float*)d_in[23];
    const float* Wn1    = (const float*)d_in[24];
    const float* bn1    = (const float*)d_in[25];
    const float* Wn2    = (const float*)d_in[26];
    const float* bn2    = (const float*)d_in[27];

    const int* row = ei;
    const int* col = ei + EE;

    float* out = (float*)d_out;
    float* out_y   = out;                        // [N,4]
    float* node_h  = out + (size_t)NN * 4;       // [N,20]
    float* node_c  = out + (size_t)NN * 24;      // [N,20]
    float* edge_h  = out + (size_t)NN * 44;      // [N,8]
    float* edge_c  = out + (size_t)NN * 52;      // [N,8]

    int nb_n = (NN + 255) / 256;
    int nb_e = (EE + 255) / 256;

    // ---- workspace layout ----
    // xu16 bf16[N][40] | full16 bf16[N][32] | agg f32[N*32] | cntf[N] | agg2[N*32] |
    // count,cursor,offset int[N] | bsum,bpre int[SBLK] | rowp,colp int[E] |
    // eap bf16[(E+4)*4]
    ushort_t* xu16   = (ushort_t*)d_ws;
    ushort_t* full16 = xu16 + (size_t)NN * 40;
    float* agg  = (float*)(full16 + (size_t)NN * 32);
    float* cntf = agg + (size_t)NN * 32;
    float* agg2 = cntf + NN;
    int* count  = (int*)(agg2 + (size_t)NN * 32);
    int* cursor = count + NN;
    int* offset = cursor + NN;
    int* bsum   = offset + NN;
    int* bpre   = bsum + SBLK;
    int* rowp   = bpre + SBLK;
    int* colp   = rowp + EE;
    ushort_t* eap = (ushort_t*)(colp + EE);
    size_t needed = (size_t)((char*)(eap + (size_t)(EE + 4) * 4) - (char*)d_ws);

    if (ws_size >= needed) {
        // zero agg | cntf | agg2 | count | cursor in one contiguous memset
        hipMemsetAsync(agg, 0, (size_t)NN * (32 + 1 + 32 + 1 + 1) * sizeof(float), stream);

        node_lstm_k<<<nb_n, 256, 0, stream>>>(x, u, hn_h, hn_c, Wih_n, Whh_n, bih_n, bhh_n,
                                              xu16, node_h, node_c);
        csr_count_k<<<nb_e, 256, 0, stream>>>(col, count);
        scan1_k<<<SBLK, 256, 0, stream>>>(count, bsum);
        scan2_k<<<1, 256, 0, stream>>>(bsum, bpre);
        scan3_k<<<SBLK, 256, 0, stream>>>(count, bpre, offset, cntf);
        csr_fill3_k<<<nb_e, 256, 0, stream>>>(row, col, eattr, offset, cursor, rowp, colp, eap);

        edge_mlp_fused_k<37, 40, 96><<<EE / 256, 256, 0, stream>>>(
            xu16, rowp, colp, eap, offset, count, We1, be1, We2, be2, agg);
        edge_lstm_k<<<nb_n, 256, 0, stream>>>(agg, cntf, he_h, he_c, Wih_e, Whh_e, bih_e, bhh_e,
                                              node_h, edge_h, edge_c, full16);
        edge_mlp_fused_k<28, 32, 64><<<EE / 256, 256, 0, stream>>>(
            full16, rowp, colp, eap, offset, count, Wo1, bo1, Wo2, bo2, agg2);
        node_out_k<<<nb_n, 256, 0, stream>>>(full16, agg2, cntf, Wn1, bn1, Wn2, bn2, out_y);
    } else {
        // fallback: atomic scatter path
        hipMemsetAsync(agg, 0, (size_t)NN * (32 + 1 + 32) * sizeof(float), stream);
        node_lstm_k<<<nb_n, 256, 0, stream>>>(x, u, hn_h, hn_c, Wih_n, Whh_n, bih_n, bhh_n,
                                              xu16, node_h, node_c);
        edge_mlp_atomic_k<37, 40, true><<<nb_e, 256, 0, stream>>>(xu16, row, col, eattr,
                                                                  We1, be1, We2, be2, agg, cntf);
        edge_lstm_k<<<nb_n, 256, 0, stream>>>(agg, cntf, he_h, he_c, Wih_e, Whh_e, bih_e, bhh_e,
                                              node_h, edge_h, edge_c, full16);
        edge_mlp_atomic_k<28, 32, false><<<nb_e, 256, 0, stream>>>(full16, row, col, eattr,
                                                                   Wo1, bo1, Wo2, bo2, agg2, nullptr);
        node_out_k<<<nb_n, 256, 0, stream>>>(full16, agg2, cntf, Wn1, bn1, Wn2, bn2, out_y);
    }
}

// Round 7
// 261.519 us; speedup vs baseline: 11.5168x; 1.1068x over previous
//
#include <hip/hip_runtime.h>
#include <math.h>

#define NN 50000
#define EE 800000
#define SBLK ((NN + 255) / 256)   // 196 scan blocks

typedef short bf16x8 __attribute__((ext_vector_type(8)));
typedef float f32x4 __attribute__((ext_vector_type(4)));
typedef unsigned short ushort_t;
#define MFMA16(a, b, c) __builtin_amdgcn_mfma_f32_16x16x32_bf16(a, b, c, 0, 0, 0)

__device__ __forceinline__ float sigmoidf_(float x) { return 1.0f / (1.0f + __expf(-x)); }

__device__ __forceinline__ unsigned short f2bf(float f) {
    unsigned u = __builtin_bit_cast(unsigned, f);
    u += 0x7FFFu + ((u >> 16) & 1u);
    return (unsigned short)(u >> 16);
}
__device__ __forceinline__ float bf2f(unsigned short v) {
    unsigned u = (unsigned)v << 16;
    return __builtin_bit_cast(float, u);
}
__device__ __forceinline__ unsigned pk2(float a, float b) {
    return ((unsigned)f2bf(b) << 16) | (unsigned)f2bf(a);
}

// packed bf16 weight table sizes (bf16 elements)
#define W1ST_A 104   // INK=96 + 8
#define W1ST_B 72    // INK=64 + 8
#define C1ST_  72
#define PW1A (64 * W1ST_A)
#define PW2A (32 * C1ST_)
#define PW1B (64 * W1ST_B)
#define PW2B (32 * C1ST_)

// ---------------- pre-pack both edge-MLP weight sets to bf16 LDS layout ----------------
__global__ __launch_bounds__(256) void pack_w_k(
    const float* __restrict__ We1, const float* __restrict__ We2,
    const float* __restrict__ Wo1, const float* __restrict__ Wo2,
    ushort_t* __restrict__ pw)
{
    ushort_t* pw1a = pw;
    ushort_t* pw2a = pw1a + PW1A;
    ushort_t* pw1b = pw2a + PW2A;
    ushort_t* pw2b = pw1b + PW1B;
    int tid = threadIdx.x;

    for (int i = tid; i < PW1A; i += 256) {
        int n = i / W1ST_A, nk = i - n * W1ST_A;
        int kp = 0; bool z = false;
        if (nk < 37) kp = nk;
        else if (nk < 40) z = true;
        else if (nk < 77) kp = nk - 3;
        else if (nk < 80) z = true;
        else if (nk < 84) kp = nk - 6;
        else z = true;
        pw1a[i] = z ? (ushort_t)0 : f2bf(We1[kp * 64 + n]);
    }
    for (int i = tid; i < PW2A; i += 256) {
        int n = i / C1ST_, k = i - n * C1ST_;
        pw2a[i] = (k < 64) ? f2bf(We2[k * 32 + n]) : (ushort_t)0;
    }
    for (int i = tid; i < PW1B; i += 256) {
        int n = i / W1ST_B, nk = i - n * W1ST_B;
        int kp = 0; bool z = false;
        if (nk < 28) kp = nk;
        else if (nk < 32) z = true;
        else if (nk < 64) kp = nk - 4;
        else z = true;
        pw1b[i] = z ? (ushort_t)0 : f2bf(Wo1[kp * 64 + n]);
    }
    for (int i = tid; i < PW2B; i += 256) {
        int n = i / C1ST_, k = i - n * C1ST_;
        pw2b[i] = (k < 64) ? f2bf(Wo2[k * 32 + n]) : (ushort_t)0;
    }
}

// ---------------- node history LSTM + bf16 padded xu table ----------------
__global__ __launch_bounds__(256) void node_lstm_k(
    const float* __restrict__ x, const float* __restrict__ u,
    const float* __restrict__ h0, const float* __restrict__ c0,
    const float* __restrict__ Wih, const float* __restrict__ Whh,
    const float* __restrict__ bih, const float* __restrict__ bhh,
    ushort_t* __restrict__ xu16, float* __restrict__ h_out, float* __restrict__ c_out)
{
    __shared__ float sWih[80 * 37];
    __shared__ float sWhh[80 * 20];
    __shared__ float sb[80];
    for (int i = threadIdx.x; i < 80 * 37; i += 256) sWih[i] = Wih[i];
    for (int i = threadIdx.x; i < 80 * 20; i += 256) sWhh[i] = Whh[i];
    if (threadIdx.x < 80) sb[threadIdx.x] = bih[threadIdx.x] + bhh[threadIdx.x];
    __syncthreads();
    int n = blockIdx.x * 256 + threadIdx.x;
    if (n >= NN) return;

    float xu[40];
#pragma unroll
    for (int k = 0; k < 5; k++) xu[k] = x[n * 5 + k];
#pragma unroll
    for (int k = 0; k < 32; k++) xu[5 + k] = u[n * 32 + k];
    xu[37] = 0.f; xu[38] = 0.f; xu[39] = 0.f;

    {
        unsigned w[20];
#pragma unroll
        for (int k = 0; k < 20; k++) w[k] = pk2(xu[2 * k], xu[2 * k + 1]);
        uint4* dst = (uint4*)(xu16 + (size_t)n * 40);
#pragma unroll
        for (int q = 0; q < 5; q++)
            dst[q] = make_uint4(w[q * 4], w[q * 4 + 1], w[q * 4 + 2], w[q * 4 + 3]);
    }

    float h[20];
#pragma unroll
    for (int k = 0; k < 20; k++) h[k] = h0[n * 20 + k];

#pragma unroll 1
    for (int r = 0; r < 20; r++) {
        float gi = sb[r], gf = sb[20 + r], gg = sb[40 + r], go = sb[60 + r];
#pragma unroll
        for (int k = 0; k < 37; k++) {
            float v = xu[k];
            gi = fmaf(v, sWih[r * 37 + k], gi);
            gf = fmaf(v, sWih[(20 + r) * 37 + k], gf);
            gg = fmaf(v, sWih[(40 + r) * 37 + k], gg);
            go = fmaf(v, sWih[(60 + r) * 37 + k], go);
        }
#pragma unroll
        for (int k = 0; k < 20; k++) {
            float v = h[k];
            gi = fmaf(v, sWhh[r * 20 + k], gi);
            gf = fmaf(v, sWhh[(20 + r) * 20 + k], gf);
            gg = fmaf(v, sWhh[(40 + r) * 20 + k], gg);
            go = fmaf(v, sWhh[(60 + r) * 20 + k], go);
        }
        float cr = c0[n * 20 + r];
        float cn = sigmoidf_(gf) * cr + sigmoidf_(gi) * tanhf(gg);
        float hn = sigmoidf_(go) * tanhf(cn);
        h_out[n * 20 + r] = hn;
        c_out[n * 20 + r] = cn;
    }
}

// ---------------- CSR build ----------------
__global__ __launch_bounds__(256) void csr_count_k(const int* __restrict__ col,
                                                   int* __restrict__ count)
{
    int e = blockIdx.x * 256 + threadIdx.x;
    if (e < EE) atomicAdd(&count[col[e]], 1);
}

__global__ __launch_bounds__(256) void scan1_k(const int* __restrict__ count,
                                               int* __restrict__ bsum)
{
    __shared__ int red[256];
    int t = threadIdx.x;
    int i = blockIdx.x * 256 + t;
    red[t] = (i < NN) ? count[i] : 0;
    __syncthreads();
#pragma unroll
    for (int d = 128; d > 0; d >>= 1) {
        if (t < d) red[t] += red[t + d];
        __syncthreads();
    }
    if (t == 0) bsum[blockIdx.x] = red[0];
}

__global__ __launch_bounds__(256) void scan2_k(const int* __restrict__ bsum,
                                               int* __restrict__ bpre)
{
    __shared__ int s[256];
    int t = threadIdx.x;
    int v = (t < SBLK) ? bsum[t] : 0;
    s[t] = v;
    __syncthreads();
#pragma unroll
    for (int d = 1; d < 256; d <<= 1) {
        int w = (t >= d) ? s[t - d] : 0;
        __syncthreads();
        s[t] += w;
        __syncthreads();
    }
    if (t < SBLK) bpre[t] = s[t] - v;
}

__global__ __launch_bounds__(256) void scan3_k(const int* __restrict__ count,
                                               const int* __restrict__ bpre,
                                               int* __restrict__ offset,
                                               float* __restrict__ cntf)
{
    __shared__ int s[256];
    int t = threadIdx.x;
    int i = blockIdx.x * 256 + t;
    int v = (i < NN) ? count[i] : 0;
    s[t] = v;
    __syncthreads();
#pragma unroll
    for (int d = 1; d < 256; d <<= 1) {
        int w = (t >= d) ? s[t - d] : 0;
        __syncthreads();
        s[t] += w;
        __syncthreads();
    }
    if (i < NN) {
        offset[i] = bpre[blockIdx.x] + s[t] - v;
        cntf[i] = (float)v;
    }
}

// fill CSR: one packed uint4 {row, col, ea01, ea23} per slot
__global__ __launch_bounds__(256) void csr_fill4_k(const int* __restrict__ row,
                                                   const int* __restrict__ col,
                                                   const float* __restrict__ eattr,
                                                   const int* __restrict__ offset,
                                                   int* __restrict__ cursor,
                                                   uint4* __restrict__ edat)
{
    int e = blockIdx.x * 256 + threadIdx.x;
    if (e >= EE) return;
    int c = col[e];
    int pos = atomicAdd(&cursor[c], 1);
    int slot = offset[c] + pos;
    float4 ev = *(const float4*)&eattr[(size_t)e * 4];
    edat[slot] = make_uint4((unsigned)row[e], (unsigned)c, pk2(ev.x, ev.y), pk2(ev.z, ev.w));
}

// ---------------- fused 2-layer edge MLP + in-block segment sum ----------------
// Weights come pre-packed (bf16, LDS layout) -> staging is a straight uint4 copy.
// Gather addressing comes from one coalesced uint4 edat load per slot.
template <int F, int STRIDE, int INK>
__global__ __launch_bounds__(256, 4) void edge_mlp_fused_k(
    const ushort_t* __restrict__ feat,
    const uint4* __restrict__ edat,
    const int* __restrict__ offset, const int* __restrict__ count,
    const ushort_t* __restrict__ pw,
    const float* __restrict__ b1, const float* __restrict__ b2,
    float* __restrict__ agg)
{
    constexpr int S1 = INK / 32;
    constexpr int W1ST = INK + 8;
    constexpr int C1ST = C1ST_;
    constexpr int ABYTES = (64 * W1ST + 32 * C1ST + 4 * 32 * C1ST) * 2;
    constexpr int BBYTES = 32 * 257 * 4;            // msg tile [32 feat][257] f32
    constexpr int UBYTES = (ABYTES > BBYTES) ? ABYTES : BBYTES;
    constexpr int NU4 = (64 * W1ST + 32 * C1ST) / 8;

    __shared__ __align__(16) char ldsu[UBYTES];
    __shared__ int colLds[256];
    __shared__ unsigned char segStartA[256];
    __shared__ short segEndA[256];                  // negative => complete segment
    __shared__ int segCnt;

    ushort_t* sW1 = (ushort_t*)ldsu;                // [64][W1ST]
    ushort_t* sW2 = sW1 + 64 * W1ST;                // [32][C1ST]
    ushort_t* sC1 = sW2 + 32 * C1ST;                // [4][32][C1ST]
    float*    msgT = (float*)ldsu;                  // [32][257]

    const int tid = threadIdx.x;
    const int B0 = blockIdx.x * 256;
    if (tid == 0) segCnt = 0;
    colLds[tid] = (int)edat[B0 + tid].y;

    // stage pre-packed weights: straight uint4 copy
    {
        const uint4* src = (const uint4*)pw;
        uint4* dst = (uint4*)ldsu;
        for (int i = tid; i < NU4; i += 256) dst[i] = src[i];
    }
    __syncthreads();

    // build segment list (col is sorted within the block)
    {
        bool isStart = (tid == 0) || (colLds[tid] != colLds[tid - 1]);
        if (isStart) {
            int node = colLds[tid];
            int off = offset[node], cn = count[node];
            int e = off + cn - B0; if (e > 256) e = 256;
            bool fullseg = (off >= B0) && (off + cn <= B0 + 256);
            int j = atomicAdd(&segCnt, 1);
            segStartA[j] = (unsigned char)tid;
            segEndA[j] = (short)(fullseg ? -e : e);
        }
    }

    const int wave = tid >> 6, lane = tid & 63;
    const int lr = lane & 15, jb = lane >> 4;
    const size_t slotBase = (size_t)B0 + (size_t)wave * 64;
    const float4* b1v = (const float4*)b1;
    ushort_t* myC1 = sC1 + wave * 32 * C1ST;        // [32][C1ST]
    const float bb2_0 = b2[lr], bb2_1 = b2[16 + lr];

    f32x4 acc2a[2][2][2];                           // [half][m][n]

#pragma unroll
    for (int half = 0; half < 2; half++) {
        // gather B-fragments; addressing from one uint4 edat load per slot
        bf16x8 xf[2][S1];
#pragma unroll
        for (int ne2 = 0; ne2 < 2; ne2++) {
            size_t slot = slotBase + (size_t)(half * 2 + ne2) * 16 + lr;
            uint4 ed = edat[slot];
            const ushort_t* xr = feat + (size_t)ed.x * STRIDE;
            const ushort_t* xc = feat + (size_t)ed.y * STRIDE;
            xf[ne2][0] = *(const bf16x8*)(xr + jb * 8);
            if (F == 37) {
                const ushort_t* p1 = (jb == 0) ? (xr + 32) : (xc + (jb - 1) * 8);
                xf[ne2][1] = *(const bf16x8*)p1;
                bf16x8 v;
                if (jb < 2) {
                    v = *(const bf16x8*)((jb == 0) ? (xc + 24) : (xc + 32));
                } else if (jb == 2) {
                    uint4 t = make_uint4(ed.z, ed.w, 0u, 0u);
                    v = __builtin_bit_cast(bf16x8, t);
                } else {
                    uint4 t = make_uint4(0u, 0u, 0u, 0u);
                    v = __builtin_bit_cast(bf16x8, t);
                }
                xf[ne2][2] = v;
            } else {
                if (jb < 3) {
                    xf[ne2][1] = *(const bf16x8*)(xc + jb * 8);
                } else {
                    uint2 lo = *(const uint2*)(xc + 24);
                    uint4 t = make_uint4(lo.x, lo.y, ed.z, ed.w);
                    xf[ne2][1] = __builtin_bit_cast(bf16x8, t);
                }
            }
        }

        // layer 1: D1[hid][edge], bias in C-init
        f32x4 acc1[4][2];
#pragma unroll
        for (int mh = 0; mh < 4; mh++) {
            float4 bv = b1v[mh * 4 + jb];
            f32x4 bi = {bv.x, bv.y, bv.z, bv.w};
            acc1[mh][0] = bi; acc1[mh][1] = bi;
        }
#pragma unroll
        for (int s = 0; s < S1; s++) {
#pragma unroll
            for (int mh = 0; mh < 4; mh++) {
                bf16x8 wf = *(const bf16x8*)&sW1[(mh * 16 + lr) * W1ST + s * 32 + jb * 8];
                acc1[mh][0] = MFMA16(wf, xf[0][s], acc1[mh][0]);
                acc1[mh][1] = MFMA16(wf, xf[1][s], acc1[mh][1]);
            }
        }

        // relu -> bf16 -> packed b64 stores into wave-private C1 [edge32][hid]
#pragma unroll
        for (int mh = 0; mh < 4; mh++) {
#pragma unroll
            for (int ne2 = 0; ne2 < 2; ne2++) {
                f32x4 a = acc1[mh][ne2];
                unsigned w0 = pk2(fmaxf(a[0], 0.f), fmaxf(a[1], 0.f));
                unsigned w1 = pk2(fmaxf(a[2], 0.f), fmaxf(a[3], 0.f));
                *(uint2*)&myC1[(ne2 * 16 + lr) * C1ST + mh * 16 + jb * 4] = make_uint2(w0, w1);
            }
        }

        // layer 2: D2[edge][hid2], bias in C-init
#pragma unroll
        for (int m = 0; m < 2; m++) {
            acc2a[half][m][0] = f32x4{bb2_0, bb2_0, bb2_0, bb2_0};
            acc2a[half][m][1] = f32x4{bb2_1, bb2_1, bb2_1, bb2_1};
        }
#pragma unroll
        for (int s2 = 0; s2 < 2; s2++) {
            bf16x8 w2f0 = *(const bf16x8*)&sW2[lr * C1ST + s2 * 32 + jb * 8];
            bf16x8 w2f1 = *(const bf16x8*)&sW2[(16 + lr) * C1ST + s2 * 32 + jb * 8];
#pragma unroll
            for (int m = 0; m < 2; m++) {
                bf16x8 a2 = *(const bf16x8*)&myC1[(m * 16 + lr) * C1ST + s2 * 32 + jb * 8];
                acc2a[half][m][0] = MFMA16(a2, w2f0, acc2a[half][m][0]);
                acc2a[half][m][1] = MFMA16(a2, w2f1, acc2a[half][m][1]);
            }
        }
    }

    // all waves done with sW1/sW2/sC1 -> alias the region as the msg tile
    __syncthreads();
#pragma unroll
    for (int half = 0; half < 2; half++) {
#pragma unroll
        for (int m = 0; m < 2; m++) {
            int row = wave * 64 + (half * 2 + m) * 16 + jb * 4;   // + r4
#pragma unroll
            for (int n = 0; n < 2; n++) {
                f32x4 a = acc2a[half][m][n];
                float* dst = &msgT[(size_t)(n * 16 + lr) * 257 + row];
                dst[0] = a[0]; dst[1] = a[1]; dst[2] = a[2]; dst[3] = a[3];
            }
        }
    }
    __syncthreads();

    // per-node reduction: wave w handles segments w, w+4, ...
    {
        int f = lane & 31;
        int h = lane >> 5;
        const float* mrow = msgT + (size_t)f * 257;
        int nseg = segCnt;
        for (int j = wave; j < nseg; j += 4) {
            int s = segStartA[j];
            int ev = segEndA[j];
            bool fullseg = ev < 0;
            int e = fullseg ? -ev : ev;
            int node = colLds[s];
            float sum = 0.f;
            for (int i = s + h; i < e; i += 2) sum += mrow[i];
            sum += __shfl_xor(sum, 32);
            if (lane < 32) {
                float* dst = &agg[(size_t)node * 32 + f];
                if (fullseg) *dst = sum;
                else atomicAdd(dst, sum);
            }
        }
    }
}

// ---------------- edge history LSTM + bf16 padded full table ----------------
__global__ __launch_bounds__(256) void edge_lstm_k(
    const float* __restrict__ agg, const float* __restrict__ cnt,
    const float* __restrict__ h0, const float* __restrict__ c0,
    const float* __restrict__ Wih, const float* __restrict__ Whh,
    const float* __restrict__ bih, const float* __restrict__ bhh,
    const float* __restrict__ node_h,
    float* __restrict__ h_out, float* __restrict__ c_out, ushort_t* __restrict__ full16)
{
    __shared__ float sWih[32 * 32];
    __shared__ float sWhh[32 * 8];
    __shared__ float sb[32];
    for (int i = threadIdx.x; i < 32 * 32; i += 256) sWih[i] = Wih[i];
    for (int i = threadIdx.x; i < 32 * 8; i += 256) sWhh[i] = Whh[i];
    if (threadIdx.x < 32) sb[threadIdx.x] = bih[threadIdx.x] + bhh[threadIdx.x];
    __syncthreads();
    int n = blockIdx.x * 256 + threadIdx.x;
    if (n >= NN) return;

    float inv = 1.0f / fmaxf(cnt[n], 1.0f);
    float msg[32];
#pragma unroll
    for (int k = 0; k < 32; k++) msg[k] = agg[(size_t)n * 32 + k] * inv;
    float h[8];
#pragma unroll
    for (int k = 0; k < 8; k++) h[k] = h0[n * 8 + k];

    float fl[32];
#pragma unroll
    for (int k = 0; k < 20; k++) fl[k] = node_h[n * 20 + k];
    fl[28] = 0.f; fl[29] = 0.f; fl[30] = 0.f; fl[31] = 0.f;

#pragma unroll
    for (int r = 0; r < 8; r++) {
        float gi = sb[r], gf = sb[8 + r], gg = sb[16 + r], go = sb[24 + r];
#pragma unroll
        for (int k = 0; k < 32; k++) {
            float v = msg[k];
            gi = fmaf(v, sWih[r * 32 + k], gi);
            gf = fmaf(v, sWih[(8 + r) * 32 + k], gf);
            gg = fmaf(v, sWih[(16 + r) * 32 + k], gg);
            go = fmaf(v, sWih[(24 + r) * 32 + k], go);
        }
#pragma unroll
        for (int k = 0; k < 8; k++) {
            float v = h[k];
            gi = fmaf(v, sWhh[r * 8 + k], gi);
            gf = fmaf(v, sWhh[(8 + r) * 8 + k], gf);
            gg = fmaf(v, sWhh[(16 + r) * 8 + k], gg);
            go = fmaf(v, sWhh[(24 + r) * 8 + k], go);
        }
        float cr = c0[n * 8 + r];
        float cn = sigmoidf_(gf) * cr + sigmoidf_(gi) * tanhf(gg);
        float hn = sigmoidf_(go) * tanhf(cn);
        h_out[n * 8 + r] = hn;
        c_out[n * 8 + r] = cn;
        fl[20 + r] = hn;
    }
    unsigned w[16];
#pragma unroll
    for (int k = 0; k < 16; k++) w[k] = pk2(fl[2 * k], fl[2 * k + 1]);
    uint4* dst = (uint4*)(full16 + (size_t)n * 32);
#pragma unroll
    for (int q = 0; q < 4; q++)
        dst[q] = make_uint4(w[q * 4], w[q * 4 + 1], w[q * 4 + 2], w[q * 4 + 3]);
}

// ---------------- output node MLP (reads bf16 full) ----------------
__global__ __launch_bounds__(256) void node_out_k(
    const ushort_t* __restrict__ full16, const float* __restrict__ agg2, const float* __restrict__ cnt,
    const float* __restrict__ W1, const float* __restrict__ b1,
    const float* __restrict__ W2, const float* __restrict__ b2,
    float* __restrict__ out)
{
    __shared__ __align__(16) float sW1[60 * 64];
    __shared__ __align__(16) float sW2[64 * 4];
    __shared__ float sb1[64];
    __shared__ float sb2[4];
    for (int i = threadIdx.x; i < 60 * 64; i += 256) sW1[i] = W1[i];
    for (int i = threadIdx.x; i < 64 * 4; i += 256) sW2[i] = W2[i];
    if (threadIdx.x < 64) sb1[threadIdx.x] = b1[threadIdx.x];
    if (threadIdx.x < 4) sb2[threadIdx.x] = b2[threadIdx.x];
    __syncthreads();
    int n = blockIdx.x * 256 + threadIdx.x;
    if (n >= NN) return;

    float in[60];
    const ushort_t* fr = full16 + (size_t)n * 32;
#pragma unroll
    for (int k = 0; k < 28; k++) in[k] = bf2f(fr[k]);
    float inv = 1.0f / fmaxf(cnt[n], 1.0f);
#pragma unroll
    for (int k = 0; k < 32; k++) in[28 + k] = agg2[(size_t)n * 32 + k] * inv;

    float o[4] = {sb2[0], sb2[1], sb2[2], sb2[3]};
#pragma unroll 1
    for (int j = 0; j < 64; j += 4) {
        float s[4] = {sb1[j], sb1[j + 1], sb1[j + 2], sb1[j + 3]};
#pragma unroll
        for (int k = 0; k < 60; k++) {
            float4 w = *(const float4*)&sW1[k * 64 + j];
            s[0] = fmaf(in[k], w.x, s[0]);
            s[1] = fmaf(in[k], w.y, s[1]);
            s[2] = fmaf(in[k], w.z, s[2]);
            s[3] = fmaf(in[k], w.w, s[3]);
        }
#pragma unroll
        for (int jj = 0; jj < 4; jj++) {
            float sv = fmaxf(s[jj], 0.0f);
            float4 w = *(const float4*)&sW2[(j + jj) * 4];
            o[0] = fmaf(sv, w.x, o[0]);
            o[1] = fmaf(sv, w.y, o[1]);
            o[2] = fmaf(sv, w.z, o[2]);
            o[3] = fmaf(sv, w.w, o[3]);
        }
    }
#pragma unroll
    for (int m = 0; m < 4; m++) out[n * 4 + m] = o[m];
}

// ---------------- fallback atomic edge MLP (reads bf16 tables) ----------------
template <int F, int STRIDE, bool DO_CNT>
__global__ __launch_bounds__(256) void edge_mlp_atomic_k(
    const ushort_t* __restrict__ feat,
    const int* __restrict__ row, const int* __restrict__ col,
    const float* __restrict__ eattr,
    const float* __restrict__ W1, const float* __restrict__ b1,
    const float* __restrict__ W2, const float* __restrict__ b2,
    float* __restrict__ agg, float* __restrict__ cnt)
{
    constexpr int IN = 2 * F + 4;
    __shared__ __align__(16) float sW1[IN * 64];
    __shared__ __align__(16) float sW2[64 * 32];
    __shared__ float sb1[64];
    __shared__ float sb2[32];
    for (int i = threadIdx.x; i < IN * 64; i += 256) sW1[i] = W1[i];
    for (int i = threadIdx.x; i < 64 * 32; i += 256) sW2[i] = W2[i];
    if (threadIdx.x < 64) sb1[threadIdx.x] = b1[threadIdx.x];
    if (threadIdx.x < 32) sb2[threadIdx.x] = b2[threadIdx.x];
    __syncthreads();
    int e = blockIdx.x * 256 + threadIdx.x;
    if (e >= EE) return;

    int r = row[e], c = col[e];
    float h[IN];
#pragma unroll
    for (int k = 0; k < F; k++) h[k] = bf2f(feat[(size_t)r * STRIDE + k]);
#pragma unroll
    for (int k = 0; k < F; k++) h[F + k] = bf2f(feat[(size_t)c * STRIDE + k]);
    float4 ev = *(const float4*)&eattr[(size_t)e * 4];
    h[2 * F] = ev.x; h[2 * F + 1] = ev.y; h[2 * F + 2] = ev.z; h[2 * F + 3] = ev.w;

    float out[32];
#pragma unroll
    for (int m = 0; m < 32; m++) out[m] = sb2[m];
#pragma unroll 1
    for (int j = 0; j < 64; j += 4) {
        float s[4] = {sb1[j], sb1[j + 1], sb1[j + 2], sb1[j + 3]};
#pragma unroll
        for (int k = 0; k < IN; k++) {
            float4 w = *(const float4*)&sW1[k * 64 + j];
            s[0] = fmaf(h[k], w.x, s[0]);
            s[1] = fmaf(h[k], w.y, s[1]);
            s[2] = fmaf(h[k], w.z, s[2]);
            s[3] = fmaf(h[k], w.w, s[3]);
        }
        s[0] = fmaxf(s[0], 0.f); s[1] = fmaxf(s[1], 0.f);
        s[2] = fmaxf(s[2], 0.f); s[3] = fmaxf(s[3], 0.f);
#pragma unroll
        for (int jj = 0; jj < 4; jj++) {
#pragma unroll
            for (int m = 0; m < 32; m += 4) {
                float4 w = *(const float4*)&sW2[(j + jj) * 32 + m];
                out[m]     = fmaf(s[jj], w.x, out[m]);
                out[m + 1] = fmaf(s[jj], w.y, out[m + 1]);
                out[m + 2] = fmaf(s[jj], w.z, out[m + 2]);
                out[m + 3] = fmaf(s[jj], w.w, out[m + 3]);
            }
        }
    }
    float* dst = &agg[(size_t)c * 32];
#pragma unroll
    for (int m = 0; m < 32; m++) atomicAdd(&dst[m], out[m]);
    if (DO_CNT) atomicAdd(&cnt[c], 1.0f);
}

extern "C" void kernel_launch(void* const* d_in, const int* in_sizes, int n_in,
                              void* d_out, int out_size, void* d_ws, size_t ws_size,
                              hipStream_t stream) {
    (void)in_sizes; (void)n_in; (void)out_size;
    const float* x      = (const float*)d_in[0];
    const float* u      = (const float*)d_in[1];
    const int*   ei     = (const int*)d_in[2];
    const float* eattr  = (const float*)d_in[3];
    const float* hn_h   = (const float*)d_in[4];
    const float* hn_c   = (const float*)d_in[5];
    const float* he_h   = (const float*)d_in[6];
    const float* he_c   = (const float*)d_in[7];
    const float* Wih_n  = (const float*)d_in[8];
    const float* Whh_n  = (const float*)d_in[9];
    const float* bih_n  = (const float*)d_in[10];
    const float* bhh_n  = (const float*)d_in[11];
    const float* Wih_e  = (const float*)d_in[12];
    const float* Whh_e  = (const float*)d_in[13];
    const float* bih_e  = (const float*)d_in[14];
    const float* bhh_e  = (const float*)d_in[15];
    const float* We1    = (const float*)d_in[16];
    const float* be1    = (const float*)d_in[17];
    const float* We2    = (const float*)d_in[18];
    const float* be2    = (const float*)d_in[19];
    const float* Wo1    = (const float*)d_in[20];
    const float* bo1    = (const float*)d_in[21];
    const float* Wo2    = (const float*)d_in[22];
    const float* bo2    = (const float*)d_in[23];
    const float* Wn1    = (const float*)d_in[24];
    const float* bn1    = (const float*)d_in[25];
    const float* Wn2    = (const float*)d_in[26];
    const float* bn2    = (const float*)d_in[27];

    const int* row = ei;
    const int* col = ei + EE;

    float* out = (float*)d_out;
    float* out_y   = out;                        // [N,4]
    float* node_h  = out + (size_t)NN * 4;       // [N,20]
    float* node_c  = out + (size_t)NN * 24;      // [N,20]
    float* edge_h  = out + (size_t)NN * 44;      // [N,8]
    float* edge_c  = out + (size_t)NN * 52;      // [N,8]

    int nb_n = (NN + 255) / 256;
    int nb_e = (EE + 255) / 256;

    // ---- workspace layout ----
    // xu16 bf16[N][40] | full16 bf16[N][32] | agg f32[N*32] | cntf[N] | agg2[N*32] |
    // count,cursor,offset int[N] | bsum,bpre int[SBLK] | pw bf16[packed] | edat uint4[E]
    ushort_t* xu16   = (ushort_t*)d_ws;
    ushort_t* full16 = xu16 + (size_t)NN * 40;
    float* agg  = (float*)(full16 + (size_t)NN * 32);
    float* cntf = agg + (size_t)NN * 32;
    float* agg2 = cntf + NN;
    int* count  = (int*)(agg2 + (size_t)NN * 32);
    int* cursor = count + NN;
    int* offset = cursor + NN;
    int* bsum   = offset + NN;
    int* bpre   = bsum + SBLK;
    // align pw to 16B
    size_t pw_off = ((size_t)((char*)(bpre + SBLK) - (char*)d_ws) + 15) & ~(size_t)15;
    ushort_t* pw = (ushort_t*)((char*)d_ws + pw_off);
    size_t edat_off = ((pw_off + (size_t)(PW1A + PW2A + PW1B + PW2B) * 2) + 15) & ~(size_t)15;
    uint4* edat = (uint4*)((char*)d_ws + edat_off);
    size_t needed = edat_off + (size_t)EE * 16;

    if (ws_size >= needed) {
        // zero agg | cntf | agg2 | count | cursor in one contiguous memset
        hipMemsetAsync(agg, 0, (size_t)NN * (32 + 1 + 32 + 1 + 1) * sizeof(float), stream);

        pack_w_k<<<1, 256, 0, stream>>>(We1, We2, Wo1, Wo2, pw);
        node_lstm_k<<<nb_n, 256, 0, stream>>>(x, u, hn_h, hn_c, Wih_n, Whh_n, bih_n, bhh_n,
                                              xu16, node_h, node_c);
        csr_count_k<<<nb_e, 256, 0, stream>>>(col, count);
        scan1_k<<<SBLK, 256, 0, stream>>>(count, bsum);
        scan2_k<<<1, 256, 0, stream>>>(bsum, bpre);
        scan3_k<<<SBLK, 256, 0, stream>>>(count, bpre, offset, cntf);
        csr_fill4_k<<<nb_e, 256, 0, stream>>>(row, col, eattr, offset, cursor, edat);

        edge_mlp_fused_k<37, 40, 96><<<EE / 256, 256, 0, stream>>>(
            xu16, edat, offset, count, pw, be1, be2, agg);
        edge_lstm_k<<<nb_n, 256, 0, stream>>>(agg, cntf, he_h, he_c, Wih_e, Whh_e, bih_e, bhh_e,
                                              node_h, edge_h, edge_c, full16);
        edge_mlp_fused_k<28, 32, 64><<<EE / 256, 256, 0, stream>>>(
            full16, edat, offset, count, pw + PW1A + PW2A, bo1, bo2, agg2);
        node_out_k<<<nb_n, 256, 0, stream>>>(full16, agg2, cntf, Wn1, bn1, Wn2, bn2, out_y);
    } else {
        // fallback: atomic scatter path
        hipMemsetAsync(agg, 0, (size_t)NN * (32 + 1 + 32) * sizeof(float), stream);
        node_lstm_k<<<nb_n, 256, 0, stream>>>(x, u, hn_h, hn_c, Wih_n, Whh_n, bih_n, bhh_n,
                                              xu16, node_h, node_c);
        edge_mlp_atomic_k<37, 40, true><<<nb_e, 256, 0, stream>>>(xu16, row, col, eattr,
                                                                  We1, be1, We2, be2, agg, cntf);
        edge_lstm_k<<<nb_n, 256, 0, stream>>>(agg, cntf, he_h, he_c, Wih_e, Whh_e, bih_e, bhh_e,
                                              node_h, edge_h, edge_c, full16);
        edge_mlp_atomic_k<28, 32, false><<<nb_e, 256, 0, stream>>>(full16, row, col, eattr,
                                                                   Wo1, bo1, Wo2, bo2, agg2, nullptr);
        node_out_k<<<nb_n, 256, 0, stream>>>(full16, agg2, cntf, Wn1, bn1, Wn2, bn2, out_y);
    }
}